// Round 5
// baseline (314.968 us; speedup 1.0000x reference)
//
#include <hip/hip_runtime.h>
#include <hip/hip_bf16.h>

// Problem: B=2, T=2048, D=1024, H=16, HD=64.
// Runtime-detect fp32 vs bf16 inputs; canonicalize to bf16 in ws.
// convert -> qkv gemm 128-tile (Q,K:[B,H,T,64]; V:[B,H,64,T]) ->
// flash attention (128-row q-tiles) -> out gemm 128-tile.

#define TB 2
#define TT 2048
#define TD 1024
#define TH 16
#define TM (TB * TT) // 4096

#define NEG_BIG (-1e30f)
#define SCALE_LOG2 0.18033688f  // (1/sqrt(64)) * log2(e)

typedef __attribute__((ext_vector_type(8))) short short8;
typedef __attribute__((ext_vector_type(4))) float f32x4;

__device__ __forceinline__ short f2bf(float f) {
    __hip_bfloat16 h = __float2bfloat16(f);
    return __builtin_bit_cast(short, h);
}

__device__ __forceinline__ float fast_exp2(float x) {
#if __has_builtin(__builtin_amdgcn_exp2f)
    return __builtin_amdgcn_exp2f(x);
#else
    return exp2f(x);
#endif
}

// async global->LDS, 16B per lane; lds dest must be wave-uniform base.
__device__ __forceinline__ void load_lds16(const short* g, short* l) {
    __builtin_amdgcn_global_load_lds(
        (const __attribute__((address_space(1))) unsigned int*)g,
        (__attribute__((address_space(3))) unsigned int*)l, 16, 0, 0);
}

// ---------------------------------------------------------------------------
__global__ void detect_kernel(const unsigned short* __restrict__ xq, int* __restrict__ flag)
{
    int lane = threadIdx.x; // 64 threads
    unsigned short u = xq[lane * 2];
    int e = (u >> 7) & 0xFF;
    int sane = ((e >= 100 && e <= 145) || u == 0) ? 1 : 0;
    unsigned long long b = __ballot(sane);
    if (lane == 0) *flag = (__popcll(b) >= 48) ? 1 : 0; // 1 = bf16, 0 = fp32
}

// ---------------------------------------------------------------------------
__global__ __launch_bounds__(256) void convert_kernel(
    const void* __restrict__ src, short* __restrict__ dst, int n,
    const int* __restrict__ flag)
{
    int i = (blockIdx.x * 256 + threadIdx.x) * 8;
    if (i >= n) return;
    if (*flag) {
        *(short8*)(dst + i) = *(const short8*)((const short*)src + i);
    } else {
        const float* s = (const float*)src + i;
        short8 o;
        #pragma unroll
        for (int j = 0; j < 8; ++j) o[j] = f2bf(s[j]);
        *(short8*)(dst + i) = o;
    }
}

// 4 weight tensors in one dispatch (blockIdx.y selects).
__global__ __launch_bounds__(256) void convert_w_kernel(
    const void* s0, const void* s1, const void* s2, const void* s3,
    short* d0, short* d1, short* d2, short* d3, int n,
    const int* __restrict__ flag)
{
    const void* src = (blockIdx.y == 0) ? s0 : (blockIdx.y == 1) ? s1 : (blockIdx.y == 2) ? s2 : s3;
    short* dst = (blockIdx.y == 0) ? d0 : (blockIdx.y == 1) ? d1 : (blockIdx.y == 2) ? d2 : d3;
    int i = (blockIdx.x * 256 + threadIdx.x) * 8;
    if (i >= n) return;
    if (*flag) {
        *(short8*)(dst + i) = *(const short8*)((const short*)src + i);
    } else {
        const float* s = (const float*)src + i;
        short8 o;
        #pragma unroll
        for (int j = 0; j < 8; ++j) o[j] = f2bf(s[j]);
        *(short8*)(dst + i) = o;
    }
}

// ---------------------------------------------------------------------------
// 128x128-tile GEMM core: C[m,n] = sum_k A[m,k]*B[n,k], K=1024, BK=64.
// 256 threads = 4 waves (2x2), each wave 64x64 (4x4 subtiles of 16x16).
// LDS staged via global_load_lds(16B) with XOR chunk swizzle (no padding).
// ---------------------------------------------------------------------------
#define GEMM_CORE(Aptr, Bptr) \
    const int tid = threadIdx.x; \
    const int wave = tid >> 6, lane = tid & 63; \
    const int wm = wave >> 1, wn = wave & 1; \
    const int lr = lane & 15; \
    const int mbase = blockIdx.x * 128, nbase = blockIdx.y * 128; \
    const int srow = (lane >> 3);         /* staging row-in-window */ \
    const int g4 = (lane >> 4) * 4; \
    f32x4 acc[4][4]; \
    _Pragma("unroll") for (int a = 0; a < 4; ++a) \
        _Pragma("unroll") for (int b = 0; b < 4; ++b) acc[a][b] = (f32x4){0,0,0,0}; \
    for (int k0 = 0; k0 < TD; k0 += 64) { \
        _Pragma("unroll") for (int t = 0; t < 4; ++t) { \
            int w = wave * 4 + t; \
            int r = w * 8 + srow; \
            int jc = (lane & 7) ^ (r & 7); \
            load_lds16(&Aptr[(size_t)(mbase + r) * TD + k0 + jc * 8], &As[w * 512]); \
            load_lds16(&Bptr[(size_t)(nbase + r) * TD + k0 + jc * 8], &Bs[w * 512]); \
        } \
        __syncthreads(); \
        _Pragma("unroll") for (int kk = 0; kk < 64; kk += 32) { \
            const int cc = (kk >> 3) + (lane >> 4); \
            const int csw = (cc ^ (lr & 7)) << 3; \
            short8 af[4], bf[4]; \
            _Pragma("unroll") for (int a = 0; a < 4; ++a) \
                af[a] = *(const short8*)&As[(wm * 64 + a * 16 + lr) * 64 + csw]; \
            _Pragma("unroll") for (int b = 0; b < 4; ++b) \
                bf[b] = *(const short8*)&Bs[(wn * 64 + b * 16 + lr) * 64 + csw]; \
            _Pragma("unroll") for (int a = 0; a < 4; ++a) \
                _Pragma("unroll") for (int b = 0; b < 4; ++b) \
                    acc[a][b] = __builtin_amdgcn_mfma_f32_16x16x32_bf16(af[a], bf[b], acc[a][b], 0, 0, 0); \
        } \
        __syncthreads(); \
    }

// QKV projection; Q,K out [B,H,T,64]; V out transposed [B,H,64,T].
__global__ __launch_bounds__(256) void qkv_gemm_kernel(
    const short* __restrict__ x,
    const short* __restrict__ Wq, const short* __restrict__ Wk,
    const short* __restrict__ Wv,
    short* __restrict__ Qo, short* __restrict__ Ko, short* __restrict__ Vo)
{
    const short* W = (blockIdx.z == 0) ? Wq : (blockIdx.z == 1) ? Wk : Wv;
    short* Out = (blockIdx.z == 0) ? Qo : (blockIdx.z == 1) ? Ko : Vo;
    const bool transposeV = (blockIdx.z == 2);

    __shared__ __align__(16) short As[128 * 64];
    __shared__ __align__(16) short Bs[128 * 64];

    GEMM_CORE(x, W)

    #pragma unroll
    for (int a = 0; a < 4; ++a) {
        #pragma unroll
        for (int b = 0; b < 4; ++b) {
            #pragma unroll
            for (int i = 0; i < 4; ++i) {
                int m = mbase + wm * 64 + a * 16 + g4 + i;
                int n = nbase + wn * 64 + b * 16 + lr;
                int bb = m >> 11, t = m & (TT - 1);
                int h = n >> 6, hd = n & 63;
                size_t idx;
                if (transposeV)
                    idx = ((size_t)(bb * TH + h) * 64 + hd) * TT + t;
                else
                    idx = (((size_t)(bb * TH + h) * TT + t) << 6) + hd;
                Out[idx] = f2bf(acc[a][b][i]);
            }
        }
    }
}

// Output projection; writes d_out per flag dtype.
__global__ __launch_bounds__(256) void out_gemm_kernel(
    const short* __restrict__ A, const short* __restrict__ W,
    void* __restrict__ C, const int* __restrict__ flag)
{
    __shared__ __align__(16) short As[128 * 64];
    __shared__ __align__(16) short Bs[128 * 64];

    GEMM_CORE(A, W)

    const int f = *flag; // uniform
    #pragma unroll
    for (int a = 0; a < 4; ++a) {
        #pragma unroll
        for (int b = 0; b < 4; ++b) {
            #pragma unroll
            for (int i = 0; i < 4; ++i) {
                int m = mbase + wm * 64 + a * 16 + g4 + i;
                int n = nbase + wn * 64 + b * 16 + lr;
                if (f) ((short*)C)[(size_t)m * TD + n] = f2bf(acc[a][b][i]);
                else   ((float*)C)[(size_t)m * TD + n] = acc[a][b][i];
            }
        }
    }
}

// ---------------------------------------------------------------------------
// Flash attention (causal). grid: (T/128, B*H), block 256.
// 128 q-rows per block (wave w owns rows [w*32, w*32+32), 2 frag groups).
// Heavy q-tiles dispatched first. Q,K: [B,H,T,64]; V: [B,H,64,T].
// ---------------------------------------------------------------------------
__global__ __launch_bounds__(256) void attn_kernel(
    const short* __restrict__ Q, const short* __restrict__ K,
    const short* __restrict__ V, short* __restrict__ AO)
{
    const int bh = blockIdx.y;
    const int qtile = 15 - (int)blockIdx.x;    // heavy first
    const int qbase = qtile * 128;
    const short* Qp = Q + (size_t)bh * TT * 64;
    const short* Kp = K + (size_t)bh * TT * 64;
    const short* Vp = V + (size_t)bh * 64 * TT;   // V^T: [64][TT]

    __shared__ __align__(16) short Ks[64][72];    // [s][hd]
    __shared__ __align__(16) short Vt[64][72];    // [hd][s]
    __shared__ __align__(16) short Ps[4][32][72]; // per-wave P [qrow 0..31][s]

    const int tid = threadIdx.x;
    const int wave = tid >> 6, lane = tid & 63;
    const int lr = lane & 15;
    const int lk = (lane >> 4) * 8;
    const int g4 = (lane >> 4) * 4;
    const int b = bh >> 4, h = bh & 15;

    // Q A-fragments, 2 groups of 16 rows
    short8 qf[2][2];
    #pragma unroll
    for (int g = 0; g < 2; ++g) {
        int qr = qbase + wave * 32 + g * 16 + lr;
        qf[g][0] = *(const short8*)&Qp[(size_t)qr * 64 + lk];
        qf[g][1] = *(const short8*)&Qp[(size_t)qr * 64 + 32 + lk];
    }

    f32x4 Oa[2][4];
    float m_i[2][4], l_i[2][4];
    #pragma unroll
    for (int g = 0; g < 2; ++g)
        #pragma unroll
        for (int c = 0; c < 4; ++c) {
            Oa[g][c] = (f32x4){0,0,0,0};
            m_i[g][c] = NEG_BIG; l_i[g][c] = 0.f;
        }

    const int kend = qbase + 128;
    for (int kt = 0; kt < kend; kt += 64) {
        for (int c = tid; c < 512; c += 256) {
            int r = c >> 3, col = (c & 7) * 8;
            *(short8*)&Ks[r][col] = *(const short8*)&Kp[(size_t)(kt + r) * 64 + col];
            *(short8*)&Vt[r][col] = *(const short8*)&Vp[(size_t)r * TT + kt + col];
        }
        __syncthreads();

        #pragma unroll
        for (int g = 0; g < 2; ++g) {
            const int gb = qbase + wave * 32 + g * 16;

            // S = Q K^T (4 key-subtiles), log2-scaled
            f32x4 s[4];
            #pragma unroll
            for (int c = 0; c < 4; ++c) {
                f32x4 z = {0, 0, 0, 0};
                short8 b0 = *(const short8*)&Ks[c * 16 + lr][lk];
                short8 b1 = *(const short8*)&Ks[c * 16 + lr][32 + lk];
                z = __builtin_amdgcn_mfma_f32_16x16x32_bf16(qf[g][0], b0, z, 0, 0, 0);
                z = __builtin_amdgcn_mfma_f32_16x16x32_bf16(qf[g][1], b1, z, 0, 0, 0);
                s[c] = z;
            }

            const bool needmask = (kt + 64 > gb);
            #pragma unroll
            for (int c = 0; c < 4; ++c) {
                int colg = kt + c * 16 + lr;
                #pragma unroll
                for (int i = 0; i < 4; ++i) {
                    float v = s[c][i] * SCALE_LOG2;
                    if (needmask) {
                        int rowg = gb + g4 + i;
                        if (colg > rowg) v = NEG_BIG;
                    }
                    s[c][i] = v;
                }
            }

            // online softmax (log2 domain)
            float mnew[4], alpha[4];
            #pragma unroll
            for (int i = 0; i < 4; ++i) {
                float v = fmaxf(fmaxf(s[0][i], s[1][i]), fmaxf(s[2][i], s[3][i]));
                #pragma unroll
                for (int off = 1; off < 16; off <<= 1)
                    v = fmaxf(v, __shfl_xor(v, off, 64));
                mnew[i] = fmaxf(m_i[g][i], v);
                alpha[i] = fast_exp2(m_i[g][i] - mnew[i]);
                m_i[g][i] = mnew[i];
            }

            #pragma unroll
            for (int c = 0; c < 4; ++c) {
                #pragma unroll
                for (int i = 0; i < 4; ++i) {
                    float p = fast_exp2(s[c][i] - mnew[i]);
                    s[c][i] = p;
                    Ps[wave][g * 16 + g4 + i][c * 16 + lr] = f2bf(p);
                }
            }
            #pragma unroll
            for (int i = 0; i < 4; ++i) {
                float v = s[0][i] + s[1][i] + s[2][i] + s[3][i];
                #pragma unroll
                for (int off = 1; off < 16; off <<= 1)
                    v += __shfl_xor(v, off, 64);
                l_i[g][i] = l_i[g][i] * alpha[i] + v;
            }
            #pragma unroll
            for (int c = 0; c < 4; ++c)
                #pragma unroll
                for (int i = 0; i < 4; ++i)
                    Oa[g][c][i] *= alpha[i];
        }

        __syncthreads(); // P visibility (wave-local, but uniform barrier is safe)

        // O += P V
        #pragma unroll
        for (int g = 0; g < 2; ++g) {
            #pragma unroll
            for (int kk = 0; kk < 2; ++kk) {
                short8 af = *(const short8*)&Ps[wave][g * 16 + lr][kk * 32 + lk];
                #pragma unroll
                for (int c = 0; c < 4; ++c) {
                    short8 bf = *(const short8*)&Vt[c * 16 + lr][kk * 32 + lk];
                    Oa[g][c] = __builtin_amdgcn_mfma_f32_16x16x32_bf16(af, bf, Oa[g][c], 0, 0, 0);
                }
            }
        }
        __syncthreads(); // protect Ks/Vt
    }

    // epilogue: normalize, write [B,T,D] (col = h*64 + hd)
    #pragma unroll
    for (int g = 0; g < 2; ++g) {
        #pragma unroll
        for (int c = 0; c < 4; ++c) {
            #pragma unroll
            for (int i = 0; i < 4; ++i) {
                int qr = qbase + wave * 32 + g * 16 + g4 + i;
                float v = Oa[g][c][i] / l_i[g][i];
                AO[((size_t)(b * TT + qr) << 10) + h * 64 + c * 16 + lr] = f2bf(v);
            }
        }
    }
}

// ---------------------------------------------------------------------------
extern "C" void kernel_launch(void* const* d_in, const int* in_sizes, int n_in,
                              void* d_out, int out_size, void* d_ws, size_t ws_size,
                              hipStream_t stream)
{
    char* ws = (char*)d_ws;
    int* flag = (int*)ws;
    const size_t XB  = (size_t)TM * TD * 2;   // 8 MiB bf16 x
    const size_t WB  = (size_t)TD * TD * 2;   // 2 MiB bf16 weight
    const size_t BUF = (size_t)TM * TD * 2;   // 8 MiB activation

    short* xb  = (short*)(ws + 256);
    short* Wqb = (short*)(ws + 256 + XB);
    short* Wkb = (short*)(ws + 256 + XB + WB);
    short* Wvb = (short*)(ws + 256 + XB + 2 * WB);
    short* Wob = (short*)(ws + 256 + XB + 3 * WB);
    char*  act = ws + 256 + XB + 4 * WB;
    short* Qb = (short*)(act);
    short* Kb = (short*)(act + BUF);
    short* Vb = (short*)(act + 2 * BUF);   // V^T [B,H,64,T]
    short* Ab = (short*)(act + 3 * BUF);

    detect_kernel<<<1, 64, 0, stream>>>((const unsigned short*)d_in[0], flag);

    const int NX = TM * TD, NW = TD * TD;
    convert_kernel<<<NX / 2048, 256, 0, stream>>>(d_in[0], xb, NX, flag);
    convert_w_kernel<<<dim3(NW / 2048, 4), 256, 0, stream>>>(
        d_in[1], d_in[2], d_in[3], d_in[4], Wqb, Wkb, Wvb, Wob, NW, flag);

    dim3 blk(256);
    qkv_gemm_kernel<<<dim3(TM / 128, TD / 128, 3), blk, 0, stream>>>(xb, Wqb, Wkb, Wvb, Qb, Kb, Vb);
    attn_kernel<<<dim3(TT / 128, TB * TH), blk, 0, stream>>>(Qb, Kb, Vb, Ab);
    out_gemm_kernel<<<dim3(TM / 128, TD / 128), blk, 0, stream>>>(Ab, Wob, d_out, flag);
}

// Round 6
// 254.363 us; speedup vs baseline: 1.2383x; 1.2383x over previous
//
#include <hip/hip_runtime.h>
#include <hip/hip_bf16.h>

// Problem: B=2, T=2048, D=1024, H=16, HD=64.
// Runtime-detect fp32 vs bf16 inputs; canonicalize to bf16 in ws.
// convert -> qkv gemm 128-tile (Q,K:[B,H,T,64]; V:[B,H,64,T]) ->
// flash attention (64-row q-tiles, balanced-deal grid) -> out gemm 128-tile.

#define TB 2
#define TT 2048
#define TD 1024
#define TH 16
#define TM (TB * TT) // 4096

#define NEG_BIG (-1e30f)
#define SCALE_LOG2 0.18033688f  // (1/sqrt(64)) * log2(e)

typedef __attribute__((ext_vector_type(8))) short short8;
typedef __attribute__((ext_vector_type(4))) float f32x4;

__device__ __forceinline__ short f2bf(float f) {
    __hip_bfloat16 h = __float2bfloat16(f);
    return __builtin_bit_cast(short, h);
}

__device__ __forceinline__ float fast_exp2(float x) {
#if __has_builtin(__builtin_amdgcn_exp2f)
    return __builtin_amdgcn_exp2f(x);
#else
    return exp2f(x);
#endif
}

// async global->LDS, 16B per lane; lds dest must be wave-uniform base.
__device__ __forceinline__ void load_lds16(const short* g, short* l) {
    __builtin_amdgcn_global_load_lds(
        (const __attribute__((address_space(1))) unsigned int*)g,
        (__attribute__((address_space(3))) unsigned int*)l, 16, 0, 0);
}

// ---------------------------------------------------------------------------
__global__ void detect_kernel(const unsigned short* __restrict__ xq, int* __restrict__ flag)
{
    int lane = threadIdx.x; // 64 threads
    unsigned short u = xq[lane * 2];
    int e = (u >> 7) & 0xFF;
    int sane = ((e >= 100 && e <= 145) || u == 0) ? 1 : 0;
    unsigned long long b = __ballot(sane);
    if (lane == 0) *flag = (__popcll(b) >= 48) ? 1 : 0; // 1 = bf16, 0 = fp32
}

// ---------------------------------------------------------------------------
__global__ __launch_bounds__(256) void convert_kernel(
    const void* __restrict__ src, short* __restrict__ dst, int n,
    const int* __restrict__ flag)
{
    int i = (blockIdx.x * 256 + threadIdx.x) * 8;
    if (i >= n) return;
    if (*flag) {
        *(short8*)(dst + i) = *(const short8*)((const short*)src + i);
    } else {
        const float* s = (const float*)src + i;
        short8 o;
        #pragma unroll
        for (int j = 0; j < 8; ++j) o[j] = f2bf(s[j]);
        *(short8*)(dst + i) = o;
    }
}

// 4 weight tensors in one dispatch (blockIdx.y selects).
__global__ __launch_bounds__(256) void convert_w_kernel(
    const void* s0, const void* s1, const void* s2, const void* s3,
    short* d0, short* d1, short* d2, short* d3, int n,
    const int* __restrict__ flag)
{
    const void* src = (blockIdx.y == 0) ? s0 : (blockIdx.y == 1) ? s1 : (blockIdx.y == 2) ? s2 : s3;
    short* dst = (blockIdx.y == 0) ? d0 : (blockIdx.y == 1) ? d1 : (blockIdx.y == 2) ? d2 : d3;
    int i = (blockIdx.x * 256 + threadIdx.x) * 8;
    if (i >= n) return;
    if (*flag) {
        *(short8*)(dst + i) = *(const short8*)((const short*)src + i);
    } else {
        const float* s = (const float*)src + i;
        short8 o;
        #pragma unroll
        for (int j = 0; j < 8; ++j) o[j] = f2bf(s[j]);
        *(short8*)(dst + i) = o;
    }
}

// ---------------------------------------------------------------------------
// 128x128-tile GEMM core: C[m,n] = sum_k A[m,k]*B[n,k], K=1024, BK=64.
// 256 threads = 4 waves (2x2), each wave 64x64 (4x4 subtiles of 16x16).
// LDS staged via global_load_lds(16B) with XOR chunk swizzle (no padding).
// ---------------------------------------------------------------------------
#define GEMM_CORE(Aptr, Bptr) \
    const int tid = threadIdx.x; \
    const int wave = tid >> 6, lane = tid & 63; \
    const int wm = wave >> 1, wn = wave & 1; \
    const int lr = lane & 15; \
    const int mbase = blockIdx.x * 128, nbase = blockIdx.y * 128; \
    const int srow = (lane >> 3);         /* staging row-in-window */ \
    const int g4 = (lane >> 4) * 4; \
    f32x4 acc[4][4]; \
    _Pragma("unroll") for (int a = 0; a < 4; ++a) \
        _Pragma("unroll") for (int b = 0; b < 4; ++b) acc[a][b] = (f32x4){0,0,0,0}; \
    for (int k0 = 0; k0 < TD; k0 += 64) { \
        _Pragma("unroll") for (int t = 0; t < 4; ++t) { \
            int w = wave * 4 + t; \
            int r = w * 8 + srow; \
            int jc = (lane & 7) ^ (r & 7); \
            load_lds16(&Aptr[(size_t)(mbase + r) * TD + k0 + jc * 8], &As[w * 512]); \
            load_lds16(&Bptr[(size_t)(nbase + r) * TD + k0 + jc * 8], &Bs[w * 512]); \
        } \
        __syncthreads(); \
        _Pragma("unroll") for (int kk = 0; kk < 64; kk += 32) { \
            const int cc = (kk >> 3) + (lane >> 4); \
            const int csw = (cc ^ (lr & 7)) << 3; \
            short8 af[4], bf[4]; \
            _Pragma("unroll") for (int a = 0; a < 4; ++a) \
                af[a] = *(const short8*)&As[(wm * 64 + a * 16 + lr) * 64 + csw]; \
            _Pragma("unroll") for (int b = 0; b < 4; ++b) \
                bf[b] = *(const short8*)&Bs[(wn * 64 + b * 16 + lr) * 64 + csw]; \
            _Pragma("unroll") for (int a = 0; a < 4; ++a) \
                _Pragma("unroll") for (int b = 0; b < 4; ++b) \
                    acc[a][b] = __builtin_amdgcn_mfma_f32_16x16x32_bf16(af[a], bf[b], acc[a][b], 0, 0, 0); \
        } \
        __syncthreads(); \
    }

// QKV projection; Q,K out [B,H,T,64]; V out transposed [B,H,64,T].
__global__ __launch_bounds__(256) void qkv_gemm_kernel(
    const short* __restrict__ x,
    const short* __restrict__ Wq, const short* __restrict__ Wk,
    const short* __restrict__ Wv,
    short* __restrict__ Qo, short* __restrict__ Ko, short* __restrict__ Vo)
{
    const short* W = (blockIdx.z == 0) ? Wq : (blockIdx.z == 1) ? Wk : Wv;
    short* Out = (blockIdx.z == 0) ? Qo : (blockIdx.z == 1) ? Ko : Vo;
    const bool transposeV = (blockIdx.z == 2);

    __shared__ __align__(16) short As[128 * 64];
    __shared__ __align__(16) short Bs[128 * 64];

    GEMM_CORE(x, W)

    #pragma unroll
    for (int a = 0; a < 4; ++a) {
        #pragma unroll
        for (int b = 0; b < 4; ++b) {
            #pragma unroll
            for (int i = 0; i < 4; ++i) {
                int m = mbase + wm * 64 + a * 16 + g4 + i;
                int n = nbase + wn * 64 + b * 16 + lr;
                int bb = m >> 11, t = m & (TT - 1);
                int h = n >> 6, hd = n & 63;
                size_t idx;
                if (transposeV)
                    idx = ((size_t)(bb * TH + h) * 64 + hd) * TT + t;
                else
                    idx = (((size_t)(bb * TH + h) * TT + t) << 6) + hd;
                Out[idx] = f2bf(acc[a][b][i]);
            }
        }
    }
}

// Output projection; writes d_out per flag dtype.
__global__ __launch_bounds__(256) void out_gemm_kernel(
    const short* __restrict__ A, const short* __restrict__ W,
    void* __restrict__ C, const int* __restrict__ flag)
{
    __shared__ __align__(16) short As[128 * 64];
    __shared__ __align__(16) short Bs[128 * 64];

    GEMM_CORE(A, W)

    const int f = *flag; // uniform
    #pragma unroll
    for (int a = 0; a < 4; ++a) {
        #pragma unroll
        for (int b = 0; b < 4; ++b) {
            #pragma unroll
            for (int i = 0; i < 4; ++i) {
                int m = mbase + wm * 64 + a * 16 + g4 + i;
                int n = nbase + wn * 64 + b * 16 + lr;
                if (f) ((short*)C)[(size_t)m * TD + n] = f2bf(acc[a][b][i]);
                else   ((float*)C)[(size_t)m * TD + n] = acc[a][b][i];
            }
        }
    }
}

// ---------------------------------------------------------------------------
// Flash attention (causal). grid: (32 bh, 32 q_ord), block 256, 64 q-rows.
// Balanced snake-deal: stride-256 residue classes (round-robin CU assignment)
// each sum to exactly 66 k-tiles; dispatch order is globally heavy-first.
// Q,K: [B,H,T,64]; V: [B,H,64,T] (V^T). exp2 online softmax, inf-free.
// ---------------------------------------------------------------------------
__global__ __launch_bounds__(256) void attn_kernel(
    const short* __restrict__ Q, const short* __restrict__ K,
    const short* __restrict__ V, short* __restrict__ AO)
{
    const int j = blockIdx.y, cdeal = j & 7, rdeal = j >> 3;
    const int qtile = (rdeal == 0) ? 31 - cdeal :
                      (rdeal == 1) ? 16 + cdeal :
                      (rdeal == 2) ? 15 - cdeal : cdeal;
    const int bh = blockIdx.x;
    const int qbase = qtile * 64;
    const short* Qp = Q + (size_t)bh * TT * 64;
    const short* Kp = K + (size_t)bh * TT * 64;
    const short* Vp = V + (size_t)bh * 64 * TT;   // V^T: [64][TT]

    __shared__ __align__(16) short Ks[64][72];    // [s][hd]
    __shared__ __align__(16) short Vt[64][72];    // [hd][s]
    __shared__ __align__(16) short Ps[4][16][72]; // per-wave P tile [qrow][s]

    const int tid = threadIdx.x;
    const int wave = tid >> 6, lane = tid & 63;
    const int lr = lane & 15;
    const int lk = (lane >> 4) * 8;
    const int g4 = (lane >> 4) * 4;
    const int b = bh >> 4, h = bh & 15;

    const int qrowA = qbase + wave * 16 + lr;
    const short8 qf0 = *(const short8*)&Qp[(size_t)qrowA * 64 + lk];
    const short8 qf1 = *(const short8*)&Qp[(size_t)qrowA * 64 + 32 + lk];

    f32x4 Oa[4] = {{0,0,0,0},{0,0,0,0},{0,0,0,0},{0,0,0,0}};
    float m_i[4] = {NEG_BIG, NEG_BIG, NEG_BIG, NEG_BIG};
    float l_i[4] = {0.f, 0.f, 0.f, 0.f};

    const int kend = qbase + 64;
    for (int kt = 0; kt < kend; kt += 64) {
        // stage K tile [s][hd] and V^T tile [hd][s] — both coalesced b128
        for (int c = tid; c < 512; c += 256) {
            int r = c >> 3, col = (c & 7) * 8;
            *(short8*)&Ks[r][col] = *(const short8*)&Kp[(size_t)(kt + r) * 64 + col];
            *(short8*)&Vt[r][col] = *(const short8*)&Vp[(size_t)r * TT + kt + col];
        }
        __syncthreads();

        // S = Q K^T, log2-scaled
        f32x4 s[4];
        #pragma unroll
        for (int c = 0; c < 4; ++c) {
            f32x4 z = {0, 0, 0, 0};
            short8 b0 = *(const short8*)&Ks[c * 16 + lr][lk];
            short8 b1 = *(const short8*)&Ks[c * 16 + lr][32 + lk];
            z = __builtin_amdgcn_mfma_f32_16x16x32_bf16(qf0, b0, z, 0, 0, 0);
            z = __builtin_amdgcn_mfma_f32_16x16x32_bf16(qf1, b1, z, 0, 0, 0);
            s[c] = z;
        }

        const bool diag = (kt == qbase);
        #pragma unroll
        for (int c = 0; c < 4; ++c) {
            int colg = kt + c * 16 + lr;
            #pragma unroll
            for (int i = 0; i < 4; ++i) {
                float v = s[c][i] * SCALE_LOG2;
                if (diag) {
                    int rowg = qbase + wave * 16 + g4 + i;
                    if (colg > rowg) v = NEG_BIG;
                }
                s[c][i] = v;
            }
        }

        // online softmax (log2 domain): row max over 64 cols
        float mnew[4], alpha[4];
        #pragma unroll
        for (int i = 0; i < 4; ++i) {
            float v = fmaxf(fmaxf(s[0][i], s[1][i]), fmaxf(s[2][i], s[3][i]));
            #pragma unroll
            for (int off = 1; off < 16; off <<= 1)
                v = fmaxf(v, __shfl_xor(v, off, 64));
            mnew[i] = fmaxf(m_i[i], v);
            alpha[i] = fast_exp2(m_i[i] - mnew[i]);
            m_i[i] = mnew[i];
        }

        #pragma unroll
        for (int c = 0; c < 4; ++c) {
            #pragma unroll
            for (int i = 0; i < 4; ++i) {
                float p = fast_exp2(s[c][i] - mnew[i]);
                s[c][i] = p;
                Ps[wave][g4 + i][c * 16 + lr] = f2bf(p);
            }
        }
        #pragma unroll
        for (int i = 0; i < 4; ++i) {
            float v = s[0][i] + s[1][i] + s[2][i] + s[3][i];
            #pragma unroll
            for (int off = 1; off < 16; off <<= 1)
                v += __shfl_xor(v, off, 64);
            l_i[i] = l_i[i] * alpha[i] + v;
        }
        #pragma unroll
        for (int c = 0; c < 4; ++c)
            #pragma unroll
            for (int i = 0; i < 4; ++i)
                Oa[c][i] *= alpha[i];

        __syncthreads(); // P visibility before MFMA reads

        // O += P V  (P as A-operand from LDS, V^T as B-operand)
        #pragma unroll
        for (int kk = 0; kk < 2; ++kk) {
            short8 af = *(const short8*)&Ps[wave][lr][kk * 32 + lk];
            #pragma unroll
            for (int c = 0; c < 4; ++c) {
                short8 bf = *(const short8*)&Vt[c * 16 + lr][kk * 32 + lk];
                Oa[c] = __builtin_amdgcn_mfma_f32_16x16x32_bf16(af, bf, Oa[c], 0, 0, 0);
            }
        }
        __syncthreads(); // protect Ks/Vt
    }

    // epilogue: normalize, write to [B,T,D] (col = h*64 + hd)
    #pragma unroll
    for (int c = 0; c < 4; ++c) {
        #pragma unroll
        for (int i = 0; i < 4; ++i) {
            int qr = qbase + wave * 16 + g4 + i;
            float v = Oa[c][i] / l_i[i];
            AO[((size_t)(b * TT + qr) << 10) + h * 64 + c * 16 + lr] = f2bf(v);
        }
    }
}

// ---------------------------------------------------------------------------
extern "C" void kernel_launch(void* const* d_in, const int* in_sizes, int n_in,
                              void* d_out, int out_size, void* d_ws, size_t ws_size,
                              hipStream_t stream)
{
    char* ws = (char*)d_ws;
    int* flag = (int*)ws;
    const size_t XB  = (size_t)TM * TD * 2;   // 8 MiB bf16 x
    const size_t WB  = (size_t)TD * TD * 2;   // 2 MiB bf16 weight
    const size_t BUF = (size_t)TM * TD * 2;   // 8 MiB activation

    short* xb  = (short*)(ws + 256);
    short* Wqb = (short*)(ws + 256 + XB);
    short* Wkb = (short*)(ws + 256 + XB + WB);
    short* Wvb = (short*)(ws + 256 + XB + 2 * WB);
    short* Wob = (short*)(ws + 256 + XB + 3 * WB);
    char*  act = ws + 256 + XB + 4 * WB;
    short* Qb = (short*)(act);
    short* Kb = (short*)(act + BUF);
    short* Vb = (short*)(act + 2 * BUF);   // V^T [B,H,64,T]
    short* Ab = (short*)(act + 3 * BUF);

    detect_kernel<<<1, 64, 0, stream>>>((const unsigned short*)d_in[0], flag);

    const int NX = TM * TD, NW = TD * TD;
    convert_kernel<<<NX / 2048, 256, 0, stream>>>(d_in[0], xb, NX, flag);
    convert_w_kernel<<<dim3(NW / 2048, 4), 256, 0, stream>>>(
        d_in[1], d_in[2], d_in[3], d_in[4], Wqb, Wkb, Wvb, Wob, NW, flag);

    dim3 blk(256);
    qkv_gemm_kernel<<<dim3(TM / 128, TD / 128, 3), blk, 0, stream>>>(xb, Wqb, Wkb, Wvb, Qb, Kb, Vb);
    attn_kernel<<<dim3(32, 32), blk, 0, stream>>>(Qb, Kb, Vb, Ab);
    out_gemm_kernel<<<dim3(TM / 128, TD / 128), blk, 0, stream>>>(Ab, Wob, d_out, flag);
}

// Round 7
// 226.371 us; speedup vs baseline: 1.3914x; 1.1237x over previous
//
#include <hip/hip_runtime.h>
#include <hip/hip_bf16.h>

// Problem: B=2, T=2048, D=1024, H=16, HD=64.
// Runtime-detect fp32 vs bf16 inputs; canonicalize to bf16 in ws.
// convert -> qkv gemm 128-tile (Q,K:[B,H,T,64]; V:[B,H,64,T]) ->
// flash attention (64-row q-tiles, balanced-deal grid, 2-barrier k-loop
// with register prefetch) -> out gemm 128-tile.

#define TB 2
#define TT 2048
#define TD 1024
#define TH 16
#define TM (TB * TT) // 4096

#define NEG_BIG (-1e30f)
#define SCALE_LOG2 0.18033688f  // (1/sqrt(64)) * log2(e)

typedef __attribute__((ext_vector_type(8))) short short8;
typedef __attribute__((ext_vector_type(4))) float f32x4;
typedef __attribute__((ext_vector_type(4))) unsigned short ushort4v;

__device__ __forceinline__ short f2bf(float f) {
    __hip_bfloat16 h = __float2bfloat16(f);
    return __builtin_bit_cast(short, h);
}

__device__ __forceinline__ float fast_exp2(float x) {
#if __has_builtin(__builtin_amdgcn_exp2f)
    return __builtin_amdgcn_exp2f(x);
#else
    return exp2f(x);
#endif
}

// async global->LDS, 16B per lane; lds dest must be wave-uniform base.
__device__ __forceinline__ void load_lds16(const short* g, short* l) {
    __builtin_amdgcn_global_load_lds(
        (const __attribute__((address_space(1))) unsigned int*)g,
        (__attribute__((address_space(3))) unsigned int*)l, 16, 0, 0);
}

// ---------------------------------------------------------------------------
__global__ void detect_kernel(const unsigned short* __restrict__ xq, int* __restrict__ flag)
{
    int lane = threadIdx.x; // 64 threads
    unsigned short u = xq[lane * 2];
    int e = (u >> 7) & 0xFF;
    int sane = ((e >= 100 && e <= 145) || u == 0) ? 1 : 0;
    unsigned long long b = __ballot(sane);
    if (lane == 0) *flag = (__popcll(b) >= 48) ? 1 : 0; // 1 = bf16, 0 = fp32
}

// ---------------------------------------------------------------------------
__global__ __launch_bounds__(256) void convert_kernel(
    const void* __restrict__ src, short* __restrict__ dst, int n,
    const int* __restrict__ flag)
{
    int i = (blockIdx.x * 256 + threadIdx.x) * 8;
    if (i >= n) return;
    if (*flag) {
        *(short8*)(dst + i) = *(const short8*)((const short*)src + i);
    } else {
        const float* s = (const float*)src + i;
        short8 o;
        #pragma unroll
        for (int j = 0; j < 8; ++j) o[j] = f2bf(s[j]);
        *(short8*)(dst + i) = o;
    }
}

// 4 weight tensors in one dispatch (blockIdx.y selects).
__global__ __launch_bounds__(256) void convert_w_kernel(
    const void* s0, const void* s1, const void* s2, const void* s3,
    short* d0, short* d1, short* d2, short* d3, int n,
    const int* __restrict__ flag)
{
    const void* src = (blockIdx.y == 0) ? s0 : (blockIdx.y == 1) ? s1 : (blockIdx.y == 2) ? s2 : s3;
    short* dst = (blockIdx.y == 0) ? d0 : (blockIdx.y == 1) ? d1 : (blockIdx.y == 2) ? d2 : d3;
    int i = (blockIdx.x * 256 + threadIdx.x) * 8;
    if (i >= n) return;
    if (*flag) {
        *(short8*)(dst + i) = *(const short8*)((const short*)src + i);
    } else {
        const float* s = (const float*)src + i;
        short8 o;
        #pragma unroll
        for (int j = 0; j < 8; ++j) o[j] = f2bf(s[j]);
        *(short8*)(dst + i) = o;
    }
}

// ---------------------------------------------------------------------------
// 128x128-tile GEMM core: C[m,n] = sum_k A[m,k]*B[n,k], K=1024, BK=64.
// 256 threads = 4 waves (2x2), each wave 64x64 (4x4 subtiles of 16x16).
// LDS staged via global_load_lds(16B) with XOR chunk swizzle (no padding).
// ---------------------------------------------------------------------------
#define GEMM_CORE(Aptr, Bptr) \
    const int tid = threadIdx.x; \
    const int wave = tid >> 6, lane = tid & 63; \
    const int wm = wave >> 1, wn = wave & 1; \
    const int lr = lane & 15; \
    const int mbase = blockIdx.x * 128, nbase = blockIdx.y * 128; \
    const int srow = (lane >> 3);         /* staging row-in-window */ \
    const int g4 = (lane >> 4) * 4; \
    f32x4 acc[4][4]; \
    _Pragma("unroll") for (int a = 0; a < 4; ++a) \
        _Pragma("unroll") for (int b = 0; b < 4; ++b) acc[a][b] = (f32x4){0,0,0,0}; \
    for (int k0 = 0; k0 < TD; k0 += 64) { \
        _Pragma("unroll") for (int t = 0; t < 4; ++t) { \
            int w = wave * 4 + t; \
            int r = w * 8 + srow; \
            int jc = (lane & 7) ^ (r & 7); \
            load_lds16(&Aptr[(size_t)(mbase + r) * TD + k0 + jc * 8], &As[w * 512]); \
            load_lds16(&Bptr[(size_t)(nbase + r) * TD + k0 + jc * 8], &Bs[w * 512]); \
        } \
        __syncthreads(); \
        _Pragma("unroll") for (int kk = 0; kk < 64; kk += 32) { \
            const int cc = (kk >> 3) + (lane >> 4); \
            const int csw = (cc ^ (lr & 7)) << 3; \
            short8 af[4], bf[4]; \
            _Pragma("unroll") for (int a = 0; a < 4; ++a) \
                af[a] = *(const short8*)&As[(wm * 64 + a * 16 + lr) * 64 + csw]; \
            _Pragma("unroll") for (int b = 0; b < 4; ++b) \
                bf[b] = *(const short8*)&Bs[(wn * 64 + b * 16 + lr) * 64 + csw]; \
            _Pragma("unroll") for (int a = 0; a < 4; ++a) \
                _Pragma("unroll") for (int b = 0; b < 4; ++b) \
                    acc[a][b] = __builtin_amdgcn_mfma_f32_16x16x32_bf16(af[a], bf[b], acc[a][b], 0, 0, 0); \
        } \
        __syncthreads(); \
    }

// QKV projection; Q,K out [B,H,T,64]; V out transposed [B,H,64,T].
__global__ __launch_bounds__(256) void qkv_gemm_kernel(
    const short* __restrict__ x,
    const short* __restrict__ Wq, const short* __restrict__ Wk,
    const short* __restrict__ Wv,
    short* __restrict__ Qo, short* __restrict__ Ko, short* __restrict__ Vo)
{
    const short* W = (blockIdx.z == 0) ? Wq : (blockIdx.z == 1) ? Wk : Wv;
    short* Out = (blockIdx.z == 0) ? Qo : (blockIdx.z == 1) ? Ko : Vo;
    const bool transposeV = (blockIdx.z == 2);

    __shared__ __align__(16) short As[128 * 64];
    __shared__ __align__(16) short Bs[128 * 64];

    GEMM_CORE(x, W)

    if (transposeV) {
        // acc[a][b][0..3] are 4 consecutive t for fixed (h,hd): pack 8B store
        #pragma unroll
        for (int a = 0; a < 4; ++a) {
            #pragma unroll
            for (int b = 0; b < 4; ++b) {
                int m0 = mbase + wm * 64 + a * 16 + g4;   // t base (i=0)
                int n = nbase + wn * 64 + b * 16 + lr;
                int bb = m0 >> 11, t0 = m0 & (TT - 1);
                int h = n >> 6, hd = n & 63;
                ushort4v pk;
                #pragma unroll
                for (int i = 0; i < 4; ++i) pk[i] = (unsigned short)f2bf(acc[a][b][i]);
                *(ushort4v*)&Out[((size_t)(bb * TH + h) * 64 + hd) * TT + t0] = pk;
            }
        }
    } else {
        #pragma unroll
        for (int a = 0; a < 4; ++a) {
            #pragma unroll
            for (int b = 0; b < 4; ++b) {
                #pragma unroll
                for (int i = 0; i < 4; ++i) {
                    int m = mbase + wm * 64 + a * 16 + g4 + i;
                    int n = nbase + wn * 64 + b * 16 + lr;
                    int bb = m >> 11, t = m & (TT - 1);
                    int h = n >> 6, hd = n & 63;
                    Out[(((size_t)(bb * TH + h) * TT + t) << 6) + hd] = f2bf(acc[a][b][i]);
                }
            }
        }
    }
}

// Output projection; writes d_out per flag dtype.
__global__ __launch_bounds__(256) void out_gemm_kernel(
    const short* __restrict__ A, const short* __restrict__ W,
    void* __restrict__ C, const int* __restrict__ flag)
{
    __shared__ __align__(16) short As[128 * 64];
    __shared__ __align__(16) short Bs[128 * 64];

    GEMM_CORE(A, W)

    const int f = *flag; // uniform
    #pragma unroll
    for (int a = 0; a < 4; ++a) {
        #pragma unroll
        for (int b = 0; b < 4; ++b) {
            #pragma unroll
            for (int i = 0; i < 4; ++i) {
                int m = mbase + wm * 64 + a * 16 + g4 + i;
                int n = nbase + wn * 64 + b * 16 + lr;
                if (f) ((short*)C)[(size_t)m * TD + n] = f2bf(acc[a][b][i]);
                else   ((float*)C)[(size_t)m * TD + n] = acc[a][b][i];
            }
        }
    }
}

// ---------------------------------------------------------------------------
// Flash attention (causal). grid: (32 bh, 32 q_ord), block 256, 64 q-rows.
// Balanced snake-deal; 2 barriers/k-tile; next-tile global loads issued at
// loop top into registers, LDS-written after the post-PV barrier.
// Q,K: [B,H,T,64]; V: [B,H,64,T] (V^T). exp2 online softmax, inf-free.
// ---------------------------------------------------------------------------
__global__ __launch_bounds__(256) void attn_kernel(
    const short* __restrict__ Q, const short* __restrict__ K,
    const short* __restrict__ V, short* __restrict__ AO)
{
    const int j = blockIdx.y, cdeal = j & 7, rdeal = j >> 3;
    const int qtile = (rdeal == 0) ? 31 - cdeal :
                      (rdeal == 1) ? 16 + cdeal :
                      (rdeal == 2) ? 15 - cdeal : cdeal;
    const int bh = blockIdx.x;
    const int qbase = qtile * 64;
    const short* Qp = Q + (size_t)bh * TT * 64;
    const short* Kp = K + (size_t)bh * TT * 64;
    const short* Vp = V + (size_t)bh * 64 * TT;   // V^T: [64][TT]

    __shared__ __align__(16) short Ks[64][72];    // [s][hd]
    __shared__ __align__(16) short Vt[64][72];    // [hd][s]
    __shared__ __align__(16) short Ps[4][16][72]; // per-wave P tile [qrow][s]

    const int tid = threadIdx.x;
    const int wave = tid >> 6, lane = tid & 63;
    const int lr = lane & 15;
    const int lk = (lane >> 4) * 8;
    const int g4 = (lane >> 4) * 4;
    const int b = bh >> 4, h = bh & 15;

    // per-thread staging coords (2 chunks)
    const int r0 = tid >> 3, c0 = (tid & 7) * 8;         // chunk tid
    const int r1 = (tid + 256) >> 3, c1 = c0;            // chunk tid+256

    const int qrowA = qbase + wave * 16 + lr;
    const short8 qf0 = *(const short8*)&Qp[(size_t)qrowA * 64 + lk];
    const short8 qf1 = *(const short8*)&Qp[(size_t)qrowA * 64 + 32 + lk];

    f32x4 Oa[4] = {{0,0,0,0},{0,0,0,0},{0,0,0,0},{0,0,0,0}};
    float m_i[4] = {NEG_BIG, NEG_BIG, NEG_BIG, NEG_BIG};
    float l_i[4] = {0.f, 0.f, 0.f, 0.f};

    // prologue: stage tile kt=0
    {
        short8 ka = *(const short8*)&Kp[(size_t)r0 * 64 + c0];
        short8 kb = *(const short8*)&Kp[(size_t)r1 * 64 + c1];
        short8 va = *(const short8*)&Vp[(size_t)r0 * TT + c0];
        short8 vb = *(const short8*)&Vp[(size_t)r1 * TT + c1];
        *(short8*)&Ks[r0][c0] = ka;
        *(short8*)&Ks[r1][c1] = kb;
        *(short8*)&Vt[r0][c0] = va;
        *(short8*)&Vt[r1][c1] = vb;
    }
    __syncthreads();

    const int kend = qbase + 64;
    for (int kt = 0; kt < kend; kt += 64) {
        // issue next-tile global loads early (latency overlaps compute below)
        const bool more = (kt + 64) < kend;
        short8 ka, kb, va, vb;
        if (more) {
            const int kn = kt + 64;
            ka = *(const short8*)&Kp[(size_t)(kn + r0) * 64 + c0];
            kb = *(const short8*)&Kp[(size_t)(kn + r1) * 64 + c1];
            va = *(const short8*)&Vp[(size_t)r0 * TT + kn + c0];
            vb = *(const short8*)&Vp[(size_t)r1 * TT + kn + c1];
        }

        // S = Q K^T, log2-scaled
        f32x4 s[4];
        #pragma unroll
        for (int c = 0; c < 4; ++c) {
            f32x4 z = {0, 0, 0, 0};
            short8 b0 = *(const short8*)&Ks[c * 16 + lr][lk];
            short8 b1 = *(const short8*)&Ks[c * 16 + lr][32 + lk];
            z = __builtin_amdgcn_mfma_f32_16x16x32_bf16(qf0, b0, z, 0, 0, 0);
            z = __builtin_amdgcn_mfma_f32_16x16x32_bf16(qf1, b1, z, 0, 0, 0);
            s[c] = z;
        }

        const bool diag = (kt == qbase);
        #pragma unroll
        for (int c = 0; c < 4; ++c) {
            int colg = kt + c * 16 + lr;
            #pragma unroll
            for (int i = 0; i < 4; ++i) {
                float v = s[c][i] * SCALE_LOG2;
                if (diag) {
                    int rowg = qbase + wave * 16 + g4 + i;
                    if (colg > rowg) v = NEG_BIG;
                }
                s[c][i] = v;
            }
        }

        // online softmax (log2 domain): row max over 64 cols
        float mnew[4], alpha[4];
        #pragma unroll
        for (int i = 0; i < 4; ++i) {
            float v = fmaxf(fmaxf(s[0][i], s[1][i]), fmaxf(s[2][i], s[3][i]));
            #pragma unroll
            for (int off = 1; off < 16; off <<= 1)
                v = fmaxf(v, __shfl_xor(v, off, 64));
            mnew[i] = fmaxf(m_i[i], v);
            alpha[i] = fast_exp2(m_i[i] - mnew[i]);
            m_i[i] = mnew[i];
        }

        #pragma unroll
        for (int c = 0; c < 4; ++c) {
            #pragma unroll
            for (int i = 0; i < 4; ++i) {
                float p = fast_exp2(s[c][i] - mnew[i]);
                s[c][i] = p;
                Ps[wave][g4 + i][c * 16 + lr] = f2bf(p);
            }
        }
        #pragma unroll
        for (int i = 0; i < 4; ++i) {
            float v = s[0][i] + s[1][i] + s[2][i] + s[3][i];
            #pragma unroll
            for (int off = 1; off < 16; off <<= 1)
                v += __shfl_xor(v, off, 64);
            l_i[i] = l_i[i] * alpha[i] + v;
        }
        #pragma unroll
        for (int c = 0; c < 4; ++c)
            #pragma unroll
            for (int i = 0; i < 4; ++i)
                Oa[c][i] *= alpha[i];

        // NO barrier here: Ps[wave] is wave-private; same-wave DS ops are
        // ordered (compiler inserts lgkmcnt for the may-aliasing read below).

        // O += P V  (P as A-operand from LDS, V^T as B-operand)
        #pragma unroll
        for (int kk = 0; kk < 2; ++kk) {
            short8 af = *(const short8*)&Ps[wave][lr][kk * 32 + lk];
            #pragma unroll
            for (int c = 0; c < 4; ++c) {
                short8 bf = *(const short8*)&Vt[c * 16 + lr][kk * 32 + lk];
                Oa[c] = __builtin_amdgcn_mfma_f32_16x16x32_bf16(af, bf, Oa[c], 0, 0, 0);
            }
        }
        __syncthreads(); // all waves done reading Ks/Vt

        if (more) {
            *(short8*)&Ks[r0][c0] = ka;
            *(short8*)&Ks[r1][c1] = kb;
            *(short8*)&Vt[r0][c0] = va;
            *(short8*)&Vt[r1][c1] = vb;
            __syncthreads(); // staged writes visible
        }
    }

    // epilogue: normalize, write to [B,T,D] (col = h*64 + hd)
    #pragma unroll
    for (int c = 0; c < 4; ++c) {
        #pragma unroll
        for (int i = 0; i < 4; ++i) {
            int qr = qbase + wave * 16 + g4 + i;
            float v = Oa[c][i] / l_i[i];
            AO[((size_t)(b * TT + qr) << 10) + h * 64 + c * 16 + lr] = f2bf(v);
        }
    }
}

// ---------------------------------------------------------------------------
extern "C" void kernel_launch(void* const* d_in, const int* in_sizes, int n_in,
                              void* d_out, int out_size, void* d_ws, size_t ws_size,
                              hipStream_t stream)
{
    char* ws = (char*)d_ws;
    int* flag = (int*)ws;
    const size_t XB  = (size_t)TM * TD * 2;   // 8 MiB bf16 x
    const size_t WB  = (size_t)TD * TD * 2;   // 2 MiB bf16 weight
    const size_t BUF = (size_t)TM * TD * 2;   // 8 MiB activation

    short* xb  = (short*)(ws + 256);
    short* Wqb = (short*)(ws + 256 + XB);
    short* Wkb = (short*)(ws + 256 + XB + WB);
    short* Wvb = (short*)(ws + 256 + XB + 2 * WB);
    short* Wob = (short*)(ws + 256 + XB + 3 * WB);
    char*  act = ws + 256 + XB + 4 * WB;
    short* Qb = (short*)(act);
    short* Kb = (short*)(act + BUF);
    short* Vb = (short*)(act + 2 * BUF);   // V^T [B,H,64,T]
    short* Ab = (short*)(act + 3 * BUF);

    detect_kernel<<<1, 64, 0, stream>>>((const unsigned short*)d_in[0], flag);

    const int NX = TM * TD, NW = TD * TD;
    convert_kernel<<<NX / 2048, 256, 0, stream>>>(d_in[0], xb, NX, flag);
    convert_w_kernel<<<dim3(NW / 2048, 4), 256, 0, stream>>>(
        d_in[1], d_in[2], d_in[3], d_in[4], Wqb, Wkb, Wvb, Wob, NW, flag);

    dim3 blk(256);
    qkv_gemm_kernel<<<dim3(TM / 128, TD / 128, 3), blk, 0, stream>>>(xb, Wqb, Wkb, Wvb, Qb, Kb, Vb);
    attn_kernel<<<dim3(32, 32), blk, 0, stream>>>(Qb, Kb, Vb, Ab);
    out_gemm_kernel<<<dim3(TM / 128, TD / 128), blk, 0, stream>>>(Ab, Wob, d_out, flag);
}

// Round 8
// 208.146 us; speedup vs baseline: 1.5132x; 1.0876x over previous
//
#include <hip/hip_runtime.h>
#include <hip/hip_bf16.h>

// Problem: B=2, T=2048, D=1024, H=16, HD=64.
// Runtime-detect fp32 vs bf16 inputs (inline, per-wave); canonicalize to bf16.
// convert_all -> qkv gemm 128-tile (Q,K:[B,H,T,64]; V:[B,H,64,T]) ->
// flash attention (S^T orientation softmax, 64-row q-tiles, balanced deal,
// register prefetch, 2 barriers/k-tile) -> out gemm 128-tile.

#define TB 2
#define TT 2048
#define TD 1024
#define TH 16
#define TM (TB * TT) // 4096

#define NEG_BIG (-1e30f)
#define SCALE_LOG2 0.18033688f  // (1/sqrt(64)) * log2(e)

typedef __attribute__((ext_vector_type(8))) short short8;
typedef __attribute__((ext_vector_type(4))) float f32x4;
typedef __attribute__((ext_vector_type(4))) unsigned short ushort4v;

__device__ __forceinline__ short f2bf(float f) {
    __hip_bfloat16 h = __float2bfloat16(f);
    return __builtin_bit_cast(short, h);
}

__device__ __forceinline__ float fast_exp2(float x) {
#if __has_builtin(__builtin_amdgcn_exp2f)
    return __builtin_amdgcn_exp2f(x);
#else
    return exp2f(x);
#endif
}

// async global->LDS, 16B per lane; lds dest must be wave-uniform base.
__device__ __forceinline__ void load_lds16(const short* g, short* l) {
    __builtin_amdgcn_global_load_lds(
        (const __attribute__((address_space(1))) unsigned int*)g,
        (__attribute__((address_space(3))) unsigned int*)l, 16, 0, 0);
}

// Inline dtype detect: sample even u16s of x. bf16 N(0,1) -> sane exponents;
// fp32 -> even u16 is random mantissa bits, ~18% sane. Uniform per wave.
__device__ __forceinline__ int detect_bf16(const unsigned short* xq) {
    int lane = threadIdx.x & 63;
    unsigned short u = xq[lane * 2];
    int e = (u >> 7) & 0xFF;
    int sane = ((e >= 100 && e <= 145) || u == 0) ? 1 : 0;
    unsigned long long b = __ballot(sane);
    return (__popcll(b) >= 48) ? 1 : 0; // 1 = bf16, 0 = fp32
}

// ---------------------------------------------------------------------------
// One dispatch converts x + 4 weights. Region by blockIdx.x:
// [0,2048) x ; then 4 x 512 blocks for Wq,Wk,Wv,Wo. 2048 elems/block.
// ---------------------------------------------------------------------------
__global__ __launch_bounds__(256) void convert_all_kernel(
    const void* __restrict__ x,  const void* __restrict__ wq,
    const void* __restrict__ wk, const void* __restrict__ wv,
    const void* __restrict__ wo,
    short* __restrict__ xb, short* __restrict__ wqb, short* __restrict__ wkb,
    short* __restrict__ wvb, short* __restrict__ wob)
{
    const int f = detect_bf16((const unsigned short*)x);
    int bid = blockIdx.x;
    const void* src; short* dst; int base;
    if (bid < 2048) { src = x; dst = xb; base = bid; }
    else {
        int w = (bid - 2048) >> 9, lb = (bid - 2048) & 511;
        src = (w == 0) ? wq : (w == 1) ? wk : (w == 2) ? wv : wo;
        dst = (w == 0) ? wqb : (w == 1) ? wkb : (w == 2) ? wvb : wob;
        base = lb;
    }
    int i = (base * 256 + (int)threadIdx.x) * 8;
    if (f) {
        *(short8*)(dst + i) = *(const short8*)((const short*)src + i);
    } else {
        const float* s = (const float*)src + i;
        short8 o;
        #pragma unroll
        for (int j = 0; j < 8; ++j) o[j] = f2bf(s[j]);
        *(short8*)(dst + i) = o;
    }
}

// ---------------------------------------------------------------------------
// 128x128-tile GEMM core: C[m,n] = sum_k A[m,k]*B[n,k], K=1024, BK=64.
// 256 threads = 4 waves (2x2), each wave 64x64 (4x4 subtiles of 16x16).
// LDS staged via global_load_lds(16B) with XOR chunk swizzle (no padding).
// ---------------------------------------------------------------------------
#define GEMM_CORE(Aptr, Bptr) \
    const int tid = threadIdx.x; \
    const int wave = tid >> 6, lane = tid & 63; \
    const int wm = wave >> 1, wn = wave & 1; \
    const int lr = lane & 15; \
    const int mbase = blockIdx.x * 128, nbase = blockIdx.y * 128; \
    const int srow = (lane >> 3);         /* staging row-in-window */ \
    const int g4 = (lane >> 4) * 4; \
    f32x4 acc[4][4]; \
    _Pragma("unroll") for (int a = 0; a < 4; ++a) \
        _Pragma("unroll") for (int b = 0; b < 4; ++b) acc[a][b] = (f32x4){0,0,0,0}; \
    for (int k0 = 0; k0 < TD; k0 += 64) { \
        _Pragma("unroll") for (int t = 0; t < 4; ++t) { \
            int w = wave * 4 + t; \
            int r = w * 8 + srow; \
            int jc = (lane & 7) ^ (r & 7); \
            load_lds16(&Aptr[(size_t)(mbase + r) * TD + k0 + jc * 8], &As[w * 512]); \
            load_lds16(&Bptr[(size_t)(nbase + r) * TD + k0 + jc * 8], &Bs[w * 512]); \
        } \
        __syncthreads(); \
        _Pragma("unroll") for (int kk = 0; kk < 64; kk += 32) { \
            const int cc = (kk >> 3) + (lane >> 4); \
            const int csw = (cc ^ (lr & 7)) << 3; \
            short8 af[4], bf[4]; \
            _Pragma("unroll") for (int a = 0; a < 4; ++a) \
                af[a] = *(const short8*)&As[(wm * 64 + a * 16 + lr) * 64 + csw]; \
            _Pragma("unroll") for (int b = 0; b < 4; ++b) \
                bf[b] = *(const short8*)&Bs[(wn * 64 + b * 16 + lr) * 64 + csw]; \
            _Pragma("unroll") for (int a = 0; a < 4; ++a) \
                _Pragma("unroll") for (int b = 0; b < 4; ++b) \
                    acc[a][b] = __builtin_amdgcn_mfma_f32_16x16x32_bf16(af[a], bf[b], acc[a][b], 0, 0, 0); \
        } \
        __syncthreads(); \
    }

// QKV projection; Q,K out [B,H,T,64]; V out transposed [B,H,64,T].
__global__ __launch_bounds__(256) void qkv_gemm_kernel(
    const short* __restrict__ x,
    const short* __restrict__ Wq, const short* __restrict__ Wk,
    const short* __restrict__ Wv,
    short* __restrict__ Qo, short* __restrict__ Ko, short* __restrict__ Vo)
{
    const short* W = (blockIdx.z == 0) ? Wq : (blockIdx.z == 1) ? Wk : Wv;
    short* Out = (blockIdx.z == 0) ? Qo : (blockIdx.z == 1) ? Ko : Vo;
    const bool transposeV = (blockIdx.z == 2);

    __shared__ __align__(16) short As[128 * 64];
    __shared__ __align__(16) short Bs[128 * 64];

    GEMM_CORE(x, W)

    if (transposeV) {
        // acc[a][b][0..3] are 4 consecutive t for fixed (h,hd): pack 8B store
        #pragma unroll
        for (int a = 0; a < 4; ++a) {
            #pragma unroll
            for (int b = 0; b < 4; ++b) {
                int m0 = mbase + wm * 64 + a * 16 + g4;   // t base (i=0)
                int n = nbase + wn * 64 + b * 16 + lr;
                int bb = m0 >> 11, t0 = m0 & (TT - 1);
                int h = n >> 6, hd = n & 63;
                ushort4v pk;
                #pragma unroll
                for (int i = 0; i < 4; ++i) pk[i] = (unsigned short)f2bf(acc[a][b][i]);
                *(ushort4v*)&Out[((size_t)(bb * TH + h) * 64 + hd) * TT + t0] = pk;
            }
        }
    } else {
        #pragma unroll
        for (int a = 0; a < 4; ++a) {
            #pragma unroll
            for (int b = 0; b < 4; ++b) {
                #pragma unroll
                for (int i = 0; i < 4; ++i) {
                    int m = mbase + wm * 64 + a * 16 + g4 + i;
                    int n = nbase + wn * 64 + b * 16 + lr;
                    int bb = m >> 11, t = m & (TT - 1);
                    int h = n >> 6, hd = n & 63;
                    Out[(((size_t)(bb * TH + h) * TT + t) << 6) + hd] = f2bf(acc[a][b][i]);
                }
            }
        }
    }
}

// Output projection; writes d_out per detected dtype (inline detect).
__global__ __launch_bounds__(256) void out_gemm_kernel(
    const short* __restrict__ A, const short* __restrict__ W,
    void* __restrict__ C, const unsigned short* __restrict__ xq)
{
    const int f = detect_bf16(xq); // at start: overlaps with GEMM

    __shared__ __align__(16) short As[128 * 64];
    __shared__ __align__(16) short Bs[128 * 64];

    GEMM_CORE(A, W)

    #pragma unroll
    for (int a = 0; a < 4; ++a) {
        #pragma unroll
        for (int b = 0; b < 4; ++b) {
            #pragma unroll
            for (int i = 0; i < 4; ++i) {
                int m = mbase + wm * 64 + a * 16 + g4 + i;
                int n = nbase + wn * 64 + b * 16 + lr;
                if (f) ((short*)C)[(size_t)m * TD + n] = f2bf(acc[a][b][i]);
                else   ((float*)C)[(size_t)m * TD + n] = acc[a][b][i];
            }
        }
    }
}

// ---------------------------------------------------------------------------
// Flash attention (causal). grid: (32 bh, 32 q_ord), block 256, 64 q-rows.
// S^T orientation: S^T = K·Q^T (operand-swapped MFMA) so each lane's 16
// scores share one q-row (qrow = lane&15) -> in-lane softmax reductions,
// 2 cross-quad shuffles, scalar m/l state, packed b64 P-stores.
// Balanced snake-deal; register prefetch; 2 barriers/k-tile.
// Q,K: [B,H,T,64]; V: [B,H,64,T] (V^T). exp2 online softmax, inf-free.
// ---------------------------------------------------------------------------
__global__ __launch_bounds__(256) void attn_kernel(
    const short* __restrict__ Q, const short* __restrict__ K,
    const short* __restrict__ V, short* __restrict__ AO)
{
    const int j = blockIdx.y, cdeal = j & 7, rdeal = j >> 3;
    const int qtile = (rdeal == 0) ? 31 - cdeal :
                      (rdeal == 1) ? 16 + cdeal :
                      (rdeal == 2) ? 15 - cdeal : cdeal;
    const int bh = blockIdx.x;
    const int qbase = qtile * 64;
    const short* Qp = Q + (size_t)bh * TT * 64;
    const short* Kp = K + (size_t)bh * TT * 64;
    const short* Vp = V + (size_t)bh * 64 * TT;   // V^T: [64][TT]

    __shared__ __align__(16) short Ks[64][72];    // [s][hd]
    __shared__ __align__(16) short Vt[64][72];    // [hd][s]
    __shared__ __align__(16) short Ps[4][16][72]; // per-wave P tile [qrow][s]

    const int tid = threadIdx.x;
    const int wave = tid >> 6, lane = tid & 63;
    const int lr = lane & 15;
    const int lk = (lane >> 4) * 8;
    const int g4 = (lane >> 4) * 4;
    const int b = bh >> 4, h = bh & 15;

    // per-thread staging coords (2 chunks)
    const int r0 = tid >> 3, c0 = (tid & 7) * 8;         // chunk tid
    const int r1 = (tid + 256) >> 3, c1 = c0;            // chunk tid+256

    const int qrowA = qbase + wave * 16 + lr;  // this lane's q-row (S^T col)
    const short8 qf0 = *(const short8*)&Qp[(size_t)qrowA * 64 + lk];
    const short8 qf1 = *(const short8*)&Qp[(size_t)qrowA * 64 + 32 + lk];

    f32x4 Oa[4] = {{0,0,0,0},{0,0,0,0},{0,0,0,0},{0,0,0,0}};
    float m_i = NEG_BIG, l_i = 0.f;   // scalar per-lane state (one q-row)

    // prologue: stage tile kt=0
    {
        short8 ka = *(const short8*)&Kp[(size_t)r0 * 64 + c0];
        short8 kb = *(const short8*)&Kp[(size_t)r1 * 64 + c1];
        short8 va = *(const short8*)&Vp[(size_t)r0 * TT + c0];
        short8 vb = *(const short8*)&Vp[(size_t)r1 * TT + c1];
        *(short8*)&Ks[r0][c0] = ka;
        *(short8*)&Ks[r1][c1] = kb;
        *(short8*)&Vt[r0][c0] = va;
        *(short8*)&Vt[r1][c1] = vb;
    }
    __syncthreads();

    const int kend = qbase + 64;
    for (int kt = 0; kt < kend; kt += 64) {
        // issue next-tile global loads early (latency overlaps compute below)
        const bool more = (kt + 64) < kend;
        short8 ka, kb, va, vb;
        if (more) {
            const int kn = kt + 64;
            ka = *(const short8*)&Kp[(size_t)(kn + r0) * 64 + c0];
            kb = *(const short8*)&Kp[(size_t)(kn + r1) * 64 + c1];
            va = *(const short8*)&Vp[(size_t)r0 * TT + kn + c0];
            vb = *(const short8*)&Vp[(size_t)r1 * TT + kn + c1];
        }

        // S^T = K Q^T: lane holds kcols {c*16 + g4 + i} for qrow = qrowA
        f32x4 s[4];
        #pragma unroll
        for (int c = 0; c < 4; ++c) {
            f32x4 z = {0, 0, 0, 0};
            short8 k0v = *(const short8*)&Ks[c * 16 + lr][lk];
            short8 k1v = *(const short8*)&Ks[c * 16 + lr][32 + lk];
            z = __builtin_amdgcn_mfma_f32_16x16x32_bf16(k0v, qf0, z, 0, 0, 0);
            z = __builtin_amdgcn_mfma_f32_16x16x32_bf16(k1v, qf1, z, 0, 0, 0);
            s[c] = z;
        }

        const bool diag = (kt == qbase);
        #pragma unroll
        for (int c = 0; c < 4; ++c) {
            #pragma unroll
            for (int i = 0; i < 4; ++i) {
                float v = s[c][i] * SCALE_LOG2;
                if (diag) {
                    int colg = kt + c * 16 + g4 + i;
                    if (colg > qrowA) v = NEG_BIG;
                }
                s[c][i] = v;
            }
        }

        // row max: in-lane over 16, then cross-quad (2 shuffles)
        float vmax = s[0][0];
        #pragma unroll
        for (int c = 0; c < 4; ++c)
            #pragma unroll
            for (int i = 0; i < 4; ++i) vmax = fmaxf(vmax, s[c][i]);
        vmax = fmaxf(vmax, __shfl_xor(vmax, 16, 64));
        vmax = fmaxf(vmax, __shfl_xor(vmax, 32, 64));
        float mnew = fmaxf(m_i, vmax);
        float alpha = fast_exp2(m_i - mnew); // first tile: 2^(-huge) = 0
        m_i = mnew;

        // P = 2^(S-m); packed b64 stores; in-lane sum + cross-quad
        float rsum = 0.f;
        #pragma unroll
        for (int c = 0; c < 4; ++c) {
            ushort4v pk;
            #pragma unroll
            for (int i = 0; i < 4; ++i) {
                float p = fast_exp2(s[c][i] - mnew);
                rsum += p;
                pk[i] = (unsigned short)f2bf(p);
            }
            *(ushort4v*)&Ps[wave][lr][c * 16 + g4] = pk;
        }
        rsum += __shfl_xor(rsum, 16, 64);
        rsum += __shfl_xor(rsum, 32, 64);
        l_i = l_i * alpha + rsum;

        // broadcast alpha from lane-space (qrow=lr) to O-row space (g4+i)
        float ab[4];
        #pragma unroll
        for (int i = 0; i < 4; ++i) ab[i] = __shfl(alpha, g4 + i, 64);
        #pragma unroll
        for (int c = 0; c < 4; ++c)
            #pragma unroll
            for (int i = 0; i < 4; ++i) Oa[c][i] *= ab[i];

        // NO barrier: Ps[wave] is wave-private; same-wave DS ops are ordered.

        // O += P V  (P as A-operand from LDS, V^T as B-operand)
        #pragma unroll
        for (int kk = 0; kk < 2; ++kk) {
            short8 af = *(const short8*)&Ps[wave][lr][kk * 32 + lk];
            #pragma unroll
            for (int c = 0; c < 4; ++c) {
                short8 bf = *(const short8*)&Vt[c * 16 + lr][kk * 32 + lk];
                Oa[c] = __builtin_amdgcn_mfma_f32_16x16x32_bf16(af, bf, Oa[c], 0, 0, 0);
            }
        }
        __syncthreads(); // all waves done reading Ks/Vt

        if (more) {
            *(short8*)&Ks[r0][c0] = ka;
            *(short8*)&Ks[r1][c1] = kb;
            *(short8*)&Vt[r0][c0] = va;
            *(short8*)&Vt[r1][c1] = vb;
            __syncthreads(); // staged writes visible
        }
    }

    // epilogue: broadcast 1/l to O-row space, write [B,T,D] (col = h*64 + hd)
    float lb[4];
    #pragma unroll
    for (int i = 0; i < 4; ++i) lb[i] = 1.0f / __shfl(l_i, g4 + i, 64);
    #pragma unroll
    for (int c = 0; c < 4; ++c) {
        #pragma unroll
        for (int i = 0; i < 4; ++i) {
            int qr = qbase + wave * 16 + g4 + i;
            float v = Oa[c][i] * lb[i];
            AO[((size_t)(b * TT + qr) << 10) + h * 64 + c * 16 + lr] = f2bf(v);
        }
    }
}

// ---------------------------------------------------------------------------
extern "C" void kernel_launch(void* const* d_in, const int* in_sizes, int n_in,
                              void* d_out, int out_size, void* d_ws, size_t ws_size,
                              hipStream_t stream)
{
    char* ws = (char*)d_ws;
    const size_t XB  = (size_t)TM * TD * 2;   // 8 MiB bf16 x
    const size_t WB  = (size_t)TD * TD * 2;   // 2 MiB bf16 weight
    const size_t BUF = (size_t)TM * TD * 2;   // 8 MiB activation

    short* xb  = (short*)(ws + 256);
    short* Wqb = (short*)(ws + 256 + XB);
    short* Wkb = (short*)(ws + 256 + XB + WB);
    short* Wvb = (short*)(ws + 256 + XB + 2 * WB);
    short* Wob = (short*)(ws + 256 + XB + 3 * WB);
    char*  act = ws + 256 + XB + 4 * WB;
    short* Qb = (short*)(act);
    short* Kb = (short*)(act + BUF);
    short* Vb = (short*)(act + 2 * BUF);   // V^T [B,H,64,T]
    short* Ab = (short*)(act + 3 * BUF);

    dim3 blk(256);
    convert_all_kernel<<<dim3(2048 + 4 * 512), blk, 0, stream>>>(
        d_in[0], d_in[1], d_in[2], d_in[3], d_in[4], xb, Wqb, Wkb, Wvb, Wob);
    qkv_gemm_kernel<<<dim3(TM / 128, TD / 128, 3), blk, 0, stream>>>(xb, Wqb, Wkb, Wvb, Qb, Kb, Vb);
    attn_kernel<<<dim3(32, 32), blk, 0, stream>>>(Qb, Kb, Vb, Ab);
    out_gemm_kernel<<<dim3(TM / 128, TD / 128), blk, 0, stream>>>(
        Ab, Wob, d_out, (const unsigned short*)d_in[0]);
}

// Round 9
// 192.899 us; speedup vs baseline: 1.6328x; 1.0790x over previous
//
#include <hip/hip_runtime.h>
#include <hip/hip_bf16.h>

// Problem: B=2, T=2048, D=1024, H=16, HD=64.
// Runtime-detect fp32 vs bf16 inputs (inline, per-wave); canonicalize to bf16.
// convert_all -> qkv gemm (128x128, reg-prefetch; Q,K:[B,H,T,64] via LDS-
// transposed coalesced epilogue; V:[B,H,64,T]) -> flash attention (S^T
// softmax, reg prefetch) -> out gemm (64x128, reg-prefetch, 2 blocks/CU).

#define TB 2
#define TT 2048
#define TD 1024
#define TH 16
#define TM (TB * TT) // 4096

#define NEG_BIG (-1e30f)
#define SCALE_LOG2 0.18033688f  // (1/sqrt(64)) * log2(e)

typedef __attribute__((ext_vector_type(8))) short short8;
typedef __attribute__((ext_vector_type(4))) float f32x4;
typedef __attribute__((ext_vector_type(4))) unsigned short ushort4v;

__device__ __forceinline__ short f2bf(float f) {
    __hip_bfloat16 h = __float2bfloat16(f);
    return __builtin_bit_cast(short, h);
}

__device__ __forceinline__ float fast_exp2(float x) {
#if __has_builtin(__builtin_amdgcn_exp2f)
    return __builtin_amdgcn_exp2f(x);
#else
    return exp2f(x);
#endif
}

// Inline dtype detect: sample even u16s of x. bf16 N(0,1) -> sane exponents;
// fp32 -> even u16 is random mantissa bits. Uniform per wave.
__device__ __forceinline__ int detect_bf16(const unsigned short* xq) {
    int lane = threadIdx.x & 63;
    unsigned short u = xq[lane * 2];
    int e = (u >> 7) & 0xFF;
    int sane = ((e >= 100 && e <= 145) || u == 0) ? 1 : 0;
    unsigned long long b = __ballot(sane);
    return (__popcll(b) >= 48) ? 1 : 0; // 1 = bf16, 0 = fp32
}

// ---------------------------------------------------------------------------
// One dispatch converts x + 4 weights; 8192 elems/block.
// blocks: [0,512) x ; then 4 x 128 for Wq,Wk,Wv,Wo.
// ---------------------------------------------------------------------------
__global__ __launch_bounds__(256) void convert_all_kernel(
    const void* __restrict__ x,  const void* __restrict__ wq,
    const void* __restrict__ wk, const void* __restrict__ wv,
    const void* __restrict__ wo,
    short* __restrict__ xb, short* __restrict__ wqb, short* __restrict__ wkb,
    short* __restrict__ wvb, short* __restrict__ wob)
{
    const int f = detect_bf16((const unsigned short*)x);
    int bid = blockIdx.x;
    const void* src; short* dst; int base;
    if (bid < 512) { src = x; dst = xb; base = bid; }
    else {
        int w = (bid - 512) >> 7, lb = (bid - 512) & 127;
        src = (w == 0) ? wq : (w == 1) ? wk : (w == 2) ? wv : wo;
        dst = (w == 0) ? wqb : (w == 1) ? wkb : (w == 2) ? wvb : wob;
        base = lb;
    }
    int i0 = base * 8192 + (int)threadIdx.x * 8;
    #pragma unroll
    for (int r = 0; r < 4; ++r) {
        int i = i0 + r * 2048;
        if (f) {
            *(short8*)(dst + i) = *(const short8*)((const short*)src + i);
        } else {
            const float* s = (const float*)src + i;
            short8 o;
            #pragma unroll
            for (int j = 0; j < 8; ++j) o[j] = f2bf(s[j]);
            *(short8*)(dst + i) = o;
        }
    }
}

// ---------------------------------------------------------------------------
// GEMM core, register-prefetch pipeline. C[m,n] = sum_k A[m,k]*B[n,k].
// Tile: MROWS x 128, BK=64, K=1024. 4 waves (2x2); wave tile (MROWS/2) x 64.
// Next k-tile loaded to registers at loop top, ds_written after the
// readers-done barrier (global latency overlaps the MFMA block).
// SM layout: As = SM[0 .. MROWS*64), Bs = SM + MROWS*64 (128*64).
// XOR chunk swizzle within each 64-col row (no padding).
// ---------------------------------------------------------------------------
template<int MROWS>
__device__ __forceinline__ void gemm_core_regpf(
    const short* __restrict__ A, const short* __restrict__ B,
    short* SM, int mbase, int nbase, f32x4 (*acc)[4])
{
    constexpr int TA = MROWS / 32;       // A chunk-groups (and A-frags) per wave
    short* As = SM;
    short* Bs = SM + MROWS * 64;

    const int tid = threadIdx.x;
    const int wave = tid >> 6, lane = tid & 63;
    const int wm = wave >> 1, wn = wave & 1;
    const int lr = lane & 15;
    const int srow = lane >> 3, jcl = lane & 7;

    #pragma unroll
    for (int a = 0; a < TA; ++a)
        #pragma unroll
        for (int b = 0; b < 4; ++b) acc[a][b] = (f32x4){0, 0, 0, 0};

    short8 an[TA], bn[4];
    // prologue: tile k0=0 -> regs -> LDS
    #pragma unroll
    for (int t = 0; t < TA; ++t) {
        int w = wave * TA + t, r = w * 8 + srow, jc = jcl ^ (r & 7);
        an[t] = *(const short8*)&A[(size_t)(mbase + r) * TD + jc * 8];
    }
    #pragma unroll
    for (int t = 0; t < 4; ++t) {
        int w = wave * 4 + t, r = w * 8 + srow, jc = jcl ^ (r & 7);
        bn[t] = *(const short8*)&B[(size_t)(nbase + r) * TD + jc * 8];
    }
    #pragma unroll
    for (int t = 0; t < TA; ++t) *(short8*)&As[(wave * TA + t) * 512 + lane * 8] = an[t];
    #pragma unroll
    for (int t = 0; t < 4; ++t)  *(short8*)&Bs[(wave * 4 + t) * 512 + lane * 8] = bn[t];
    __syncthreads();

    for (int k0 = 0; k0 < TD; k0 += 64) {
        const bool more = (k0 + 64) < TD;
        if (more) {
            #pragma unroll
            for (int t = 0; t < TA; ++t) {
                int w = wave * TA + t, r = w * 8 + srow, jc = jcl ^ (r & 7);
                an[t] = *(const short8*)&A[(size_t)(mbase + r) * TD + k0 + 64 + jc * 8];
            }
            #pragma unroll
            for (int t = 0; t < 4; ++t) {
                int w = wave * 4 + t, r = w * 8 + srow, jc = jcl ^ (r & 7);
                bn[t] = *(const short8*)&B[(size_t)(nbase + r) * TD + k0 + 64 + jc * 8];
            }
        }
        #pragma unroll
        for (int kk = 0; kk < 64; kk += 32) {
            const int cc = (kk >> 3) + (lane >> 4);
            const int csw = (cc ^ (lr & 7)) << 3;
            short8 af[TA], bf[4];
            #pragma unroll
            for (int a = 0; a < TA; ++a)
                af[a] = *(const short8*)&As[(wm * (MROWS / 2) + a * 16 + lr) * 64 + csw];
            #pragma unroll
            for (int b = 0; b < 4; ++b)
                bf[b] = *(const short8*)&Bs[(wn * 64 + b * 16 + lr) * 64 + csw];
            #pragma unroll
            for (int a = 0; a < TA; ++a)
                #pragma unroll
                for (int b = 0; b < 4; ++b)
                    acc[a][b] = __builtin_amdgcn_mfma_f32_16x16x32_bf16(af[a], bf[b], acc[a][b], 0, 0, 0);
        }
        __syncthreads(); // all waves done reading As/Bs
        if (more) {
            #pragma unroll
            for (int t = 0; t < TA; ++t) *(short8*)&As[(wave * TA + t) * 512 + lane * 8] = an[t];
            #pragma unroll
            for (int t = 0; t < 4; ++t)  *(short8*)&Bs[(wave * 4 + t) * 512 + lane * 8] = bn[t];
            __syncthreads(); // staged writes visible
        }
    }
}

// ---------------------------------------------------------------------------
// QKV projection; 128x128 tiles, grid (32, 8, 3) = 768 blocks (3/CU).
// Q,K out [B,H,T,64] via LDS-transposed coalesced epilogue (64B/thread runs);
// V out transposed [B,H,64,T] via packed 8B stores.
// ---------------------------------------------------------------------------
__global__ __launch_bounds__(256, 3) void qkv_gemm_kernel(
    const short* __restrict__ x,
    const short* __restrict__ Wq, const short* __restrict__ Wk,
    const short* __restrict__ Wv,
    short* __restrict__ Qo, short* __restrict__ Ko, short* __restrict__ Vo)
{
    const short* W = (blockIdx.z == 0) ? Wq : (blockIdx.z == 1) ? Wk : Wv;
    short* Out = (blockIdx.z == 0) ? Qo : (blockIdx.z == 1) ? Ko : Vo;
    const bool transposeV = (blockIdx.z == 2);

    __shared__ __align__(16) short SM[128 * 64 * 2]; // As + Bs; Cs overlay

    const int mbase = blockIdx.x * 128, nbase = blockIdx.y * 128;
    f32x4 acc[4][4];
    gemm_core_regpf<128>(x, W, SM, mbase, nbase, acc);

    const int tid = threadIdx.x;
    const int wave = tid >> 6, lane = tid & 63;
    const int wm = wave >> 1, wn = wave & 1;
    const int lr = lane & 15;
    const int g4 = (lane >> 4) * 4;

    if (transposeV) {
        // acc[a][b][0..3] are 4 consecutive t for fixed (h,hd): pack 8B store
        #pragma unroll
        for (int a = 0; a < 4; ++a) {
            #pragma unroll
            for (int b = 0; b < 4; ++b) {
                int m0 = mbase + wm * 64 + a * 16 + g4;
                int n = nbase + wn * 64 + b * 16 + lr;
                int bb = m0 >> 11, t0 = m0 & (TT - 1);
                int h = n >> 6, hd = n & 63;
                ushort4v pk;
                #pragma unroll
                for (int i = 0; i < 4; ++i) pk[i] = (unsigned short)f2bf(acc[a][b][i]);
                *(ushort4v*)&Out[((size_t)(bb * TH + h) * 64 + hd) * TT + t0] = pk;
            }
        }
    } else {
        // LDS transpose: 2 passes of 64 n-cols (= 1 head each), Cs 128x72
        short* Cs = SM;
        #pragma unroll
        for (int p = 0; p < 2; ++p) {
            __syncthreads(); // SM free / prev pass reads done
            if (wn == p) {
                #pragma unroll
                for (int a = 0; a < 4; ++a)
                    #pragma unroll
                    for (int b = 0; b < 4; ++b)
                        #pragma unroll
                        for (int i = 0; i < 4; ++i) {
                            int ml = wm * 64 + a * 16 + g4 + i;
                            int nl = b * 16 + lr;
                            Cs[ml * 72 + nl] = f2bf(acc[a][b][i]);
                        }
            }
            __syncthreads();
            // coalesced read+store: thread -> (t, 32-col half), 64B contiguous
            int tl = tid >> 1, hc = (tid & 1) * 32;
            int h = (nbase >> 6) + p;
            int m = mbase + tl;
            int bb = m >> 11, t = m & (TT - 1);
            size_t base = (((size_t)(bb * TH + h) * TT + t) << 6) + hc;
            #pragma unroll
            for (int q = 0; q < 4; ++q)
                *(short8*)&Out[base + q * 8] = *(short8*)&Cs[tl * 72 + hc + q * 8];
        }
    }
}

// ---------------------------------------------------------------------------
// Output projection; 64x128 tiles, grid (64, 8) = 512 blocks (2/CU).
// Writes d_out per detected dtype (inline detect).
// ---------------------------------------------------------------------------
__global__ __launch_bounds__(256, 2) void out_gemm_kernel(
    const short* __restrict__ A, const short* __restrict__ W,
    void* __restrict__ C, const unsigned short* __restrict__ xq)
{
    const int f = detect_bf16(xq);

    __shared__ __align__(16) short SM[64 * 64 + 128 * 64];

    const int mbase = blockIdx.x * 64, nbase = blockIdx.y * 128;
    f32x4 acc[2][4];
    gemm_core_regpf<64>(A, W, SM, mbase, nbase, acc);

    const int tid = threadIdx.x;
    const int wave = tid >> 6, lane = tid & 63;
    const int wm = wave >> 1, wn = wave & 1;
    const int lr = lane & 15;
    const int g4 = (lane >> 4) * 4;

    #pragma unroll
    for (int a = 0; a < 2; ++a) {
        #pragma unroll
        for (int b = 0; b < 4; ++b) {
            #pragma unroll
            for (int i = 0; i < 4; ++i) {
                int m = mbase + wm * 32 + a * 16 + g4 + i;
                int n = nbase + wn * 64 + b * 16 + lr;
                if (f) ((short*)C)[(size_t)m * TD + n] = f2bf(acc[a][b][i]);
                else   ((float*)C)[(size_t)m * TD + n] = acc[a][b][i];
            }
        }
    }
}

// ---------------------------------------------------------------------------
// Flash attention (causal). grid: (32 bh, 32 q_ord), block 256, 64 q-rows.
// S^T orientation (K·Q^T) -> in-lane softmax, scalar m/l, packed P stores.
// Balanced snake-deal; register prefetch; 2 barriers/k-tile. Unchanged (R8).
// ---------------------------------------------------------------------------
__global__ __launch_bounds__(256) void attn_kernel(
    const short* __restrict__ Q, const short* __restrict__ K,
    const short* __restrict__ V, short* __restrict__ AO)
{
    const int j = blockIdx.y, cdeal = j & 7, rdeal = j >> 3;
    const int qtile = (rdeal == 0) ? 31 - cdeal :
                      (rdeal == 1) ? 16 + cdeal :
                      (rdeal == 2) ? 15 - cdeal : cdeal;
    const int bh = blockIdx.x;
    const int qbase = qtile * 64;
    const short* Qp = Q + (size_t)bh * TT * 64;
    const short* Kp = K + (size_t)bh * TT * 64;
    const short* Vp = V + (size_t)bh * 64 * TT;   // V^T: [64][TT]

    __shared__ __align__(16) short Ks[64][72];
    __shared__ __align__(16) short Vt[64][72];
    __shared__ __align__(16) short Ps[4][16][72];

    const int tid = threadIdx.x;
    const int wave = tid >> 6, lane = tid & 63;
    const int lr = lane & 15;
    const int lk = (lane >> 4) * 8;
    const int g4 = (lane >> 4) * 4;
    const int b = bh >> 4, h = bh & 15;

    const int r0 = tid >> 3, c0 = (tid & 7) * 8;
    const int r1 = (tid + 256) >> 3, c1 = c0;

    const int qrowA = qbase + wave * 16 + lr;
    const short8 qf0 = *(const short8*)&Qp[(size_t)qrowA * 64 + lk];
    const short8 qf1 = *(const short8*)&Qp[(size_t)qrowA * 64 + 32 + lk];

    f32x4 Oa[4] = {{0,0,0,0},{0,0,0,0},{0,0,0,0},{0,0,0,0}};
    float m_i = NEG_BIG, l_i = 0.f;

    {
        short8 ka = *(const short8*)&Kp[(size_t)r0 * 64 + c0];
        short8 kb = *(const short8*)&Kp[(size_t)r1 * 64 + c1];
        short8 va = *(const short8*)&Vp[(size_t)r0 * TT + c0];
        short8 vb = *(const short8*)&Vp[(size_t)r1 * TT + c1];
        *(short8*)&Ks[r0][c0] = ka;
        *(short8*)&Ks[r1][c1] = kb;
        *(short8*)&Vt[r0][c0] = va;
        *(short8*)&Vt[r1][c1] = vb;
    }
    __syncthreads();

    const int kend = qbase + 64;
    for (int kt = 0; kt < kend; kt += 64) {
        const bool more = (kt + 64) < kend;
        short8 ka, kb, va, vb;
        if (more) {
            const int kn = kt + 64;
            ka = *(const short8*)&Kp[(size_t)(kn + r0) * 64 + c0];
            kb = *(const short8*)&Kp[(size_t)(kn + r1) * 64 + c1];
            va = *(const short8*)&Vp[(size_t)r0 * TT + kn + c0];
            vb = *(const short8*)&Vp[(size_t)r1 * TT + kn + c1];
        }

        f32x4 s[4];
        #pragma unroll
        for (int c = 0; c < 4; ++c) {
            f32x4 z = {0, 0, 0, 0};
            short8 k0v = *(const short8*)&Ks[c * 16 + lr][lk];
            short8 k1v = *(const short8*)&Ks[c * 16 + lr][32 + lk];
            z = __builtin_amdgcn_mfma_f32_16x16x32_bf16(k0v, qf0, z, 0, 0, 0);
            z = __builtin_amdgcn_mfma_f32_16x16x32_bf16(k1v, qf1, z, 0, 0, 0);
            s[c] = z;
        }

        const bool diag = (kt == qbase);
        #pragma unroll
        for (int c = 0; c < 4; ++c) {
            #pragma unroll
            for (int i = 0; i < 4; ++i) {
                float v = s[c][i] * SCALE_LOG2;
                if (diag) {
                    int colg = kt + c * 16 + g4 + i;
                    if (colg > qrowA) v = NEG_BIG;
                }
                s[c][i] = v;
            }
        }

        float vmax = s[0][0];
        #pragma unroll
        for (int c = 0; c < 4; ++c)
            #pragma unroll
            for (int i = 0; i < 4; ++i) vmax = fmaxf(vmax, s[c][i]);
        vmax = fmaxf(vmax, __shfl_xor(vmax, 16, 64));
        vmax = fmaxf(vmax, __shfl_xor(vmax, 32, 64));
        float mnew = fmaxf(m_i, vmax);
        float alpha = fast_exp2(m_i - mnew);
        m_i = mnew;

        float rsum = 0.f;
        #pragma unroll
        for (int c = 0; c < 4; ++c) {
            ushort4v pk;
            #pragma unroll
            for (int i = 0; i < 4; ++i) {
                float p = fast_exp2(s[c][i] - mnew);
                rsum += p;
                pk[i] = (unsigned short)f2bf(p);
            }
            *(ushort4v*)&Ps[wave][lr][c * 16 + g4] = pk;
        }
        rsum += __shfl_xor(rsum, 16, 64);
        rsum += __shfl_xor(rsum, 32, 64);
        l_i = l_i * alpha + rsum;

        float ab[4];
        #pragma unroll
        for (int i = 0; i < 4; ++i) ab[i] = __shfl(alpha, g4 + i, 64);
        #pragma unroll
        for (int c = 0; c < 4; ++c)
            #pragma unroll
            for (int i = 0; i < 4; ++i) Oa[c][i] *= ab[i];

        #pragma unroll
        for (int kk = 0; kk < 2; ++kk) {
            short8 af = *(const short8*)&Ps[wave][lr][kk * 32 + lk];
            #pragma unroll
            for (int c = 0; c < 4; ++c) {
                short8 bf = *(const short8*)&Vt[c * 16 + lr][kk * 32 + lk];
                Oa[c] = __builtin_amdgcn_mfma_f32_16x16x32_bf16(af, bf, Oa[c], 0, 0, 0);
            }
        }
        __syncthreads();

        if (more) {
            *(short8*)&Ks[r0][c0] = ka;
            *(short8*)&Ks[r1][c1] = kb;
            *(short8*)&Vt[r0][c0] = va;
            *(short8*)&Vt[r1][c1] = vb;
            __syncthreads();
        }
    }

    float lb[4];
    #pragma unroll
    for (int i = 0; i < 4; ++i) lb[i] = 1.0f / __shfl(l_i, g4 + i, 64);
    #pragma unroll
    for (int c = 0; c < 4; ++c) {
        #pragma unroll
        for (int i = 0; i < 4; ++i) {
            int qr = qbase + wave * 16 + g4 + i;
            float v = Oa[c][i] * lb[i];
            AO[((size_t)(b * TT + qr) << 10) + h * 64 + c * 16 + lr] = f2bf(v);
        }
    }
}

// ---------------------------------------------------------------------------
extern "C" void kernel_launch(void* const* d_in, const int* in_sizes, int n_in,
                              void* d_out, int out_size, void* d_ws, size_t ws_size,
                              hipStream_t stream)
{
    char* ws = (char*)d_ws;
    const size_t XB  = (size_t)TM * TD * 2;   // 8 MiB bf16 x
    const size_t WB  = (size_t)TD * TD * 2;   // 2 MiB bf16 weight
    const size_t BUF = (size_t)TM * TD * 2;   // 8 MiB activation

    short* xb  = (short*)(ws + 256);
    short* Wqb = (short*)(ws + 256 + XB);
    short* Wkb = (short*)(ws + 256 + XB + WB);
    short* Wvb = (short*)(ws + 256 + XB + 2 * WB);
    short* Wob = (short*)(ws + 256 + XB + 3 * WB);
    char*  act = ws + 256 + XB + 4 * WB;
    short* Qb = (short*)(act);
    short* Kb = (short*)(act + BUF);
    short* Vb = (short*)(act + 2 * BUF);   // V^T [B,H,64,T]
    short* Ab = (short*)(act + 3 * BUF);

    dim3 blk(256);
    convert_all_kernel<<<dim3(512 + 4 * 128), blk, 0, stream>>>(
        d_in[0], d_in[1], d_in[2], d_in[3], d_in[4], xb, Wqb, Wkb, Wvb, Wob);
    qkv_gemm_kernel<<<dim3(TM / 128, TD / 128, 3), blk, 0, stream>>>(xb, Wqb, Wkb, Wvb, Qb, Kb, Vb);
    attn_kernel<<<dim3(32, 32), blk, 0, stream>>>(Qb, Kb, Vb, Ab);
    out_gemm_kernel<<<dim3(TM / 64, TD / 128), blk, 0, stream>>>(
        Ab, Wob, d_out, (const unsigned short*)d_in[0]);
}

// Round 10
// 188.994 us; speedup vs baseline: 1.6666x; 1.0207x over previous
//
#include <hip/hip_runtime.h>
#include <hip/hip_bf16.h>

// Problem: B=2, T=2048, D=1024, H=16, HD=64.
// Runtime-detect fp32 vs bf16 inputs (inline, per-wave); canonicalize to bf16.
// convert_all -> qkv gemm (128x128, reg-prefetch; Q,K:[B,H,T,64]; V:[B,H,64,T])
// -> split-S flash attention (2048 blocks, partial O/m/l) -> merge -> out gemm.

#define TB 2
#define TT 2048
#define TD 1024
#define TH 16
#define TM (TB * TT) // 4096

#define NEG_BIG (-1e30f)
#define SCALE_LOG2 0.18033688f  // (1/sqrt(64)) * log2(e)

typedef __attribute__((ext_vector_type(8))) short short8;
typedef __attribute__((ext_vector_type(4))) float f32x4;
typedef __attribute__((ext_vector_type(4))) unsigned short ushort4v;

__device__ __forceinline__ short f2bf(float f) {
    __hip_bfloat16 h = __float2bfloat16(f);
    return __builtin_bit_cast(short, h);
}

__device__ __forceinline__ float bf2f(short u) {
    unsigned int x = ((unsigned int)(unsigned short)u) << 16;
    return __builtin_bit_cast(float, x);
}

__device__ __forceinline__ float fast_exp2(float x) {
#if __has_builtin(__builtin_amdgcn_exp2f)
    return __builtin_amdgcn_exp2f(x);
#else
    return exp2f(x);
#endif
}

// Inline dtype detect: sample even u16s of x; uniform per wave.
__device__ __forceinline__ int detect_bf16(const unsigned short* xq) {
    int lane = threadIdx.x & 63;
    unsigned short u = xq[lane * 2];
    int e = (u >> 7) & 0xFF;
    int sane = ((e >= 100 && e <= 145) || u == 0) ? 1 : 0;
    unsigned long long b = __ballot(sane);
    return (__popcll(b) >= 48) ? 1 : 0; // 1 = bf16, 0 = fp32
}

// ---------------------------------------------------------------------------
// One dispatch converts x + 4 weights; 8192 elems/block.
// ---------------------------------------------------------------------------
__global__ __launch_bounds__(256) void convert_all_kernel(
    const void* __restrict__ x,  const void* __restrict__ wq,
    const void* __restrict__ wk, const void* __restrict__ wv,
    const void* __restrict__ wo,
    short* __restrict__ xb, short* __restrict__ wqb, short* __restrict__ wkb,
    short* __restrict__ wvb, short* __restrict__ wob)
{
    const int f = detect_bf16((const unsigned short*)x);
    int bid = blockIdx.x;
    const void* src; short* dst; int base;
    if (bid < 512) { src = x; dst = xb; base = bid; }
    else {
        int w = (bid - 512) >> 7, lb = (bid - 512) & 127;
        src = (w == 0) ? wq : (w == 1) ? wk : (w == 2) ? wv : wo;
        dst = (w == 0) ? wqb : (w == 1) ? wkb : (w == 2) ? wvb : wob;
        base = lb;
    }
    int i0 = base * 8192 + (int)threadIdx.x * 8;
    #pragma unroll
    for (int r = 0; r < 4; ++r) {
        int i = i0 + r * 2048;
        if (f) {
            *(short8*)(dst + i) = *(const short8*)((const short*)src + i);
        } else {
            const float* s = (const float*)src + i;
            short8 o;
            #pragma unroll
            for (int j = 0; j < 8; ++j) o[j] = f2bf(s[j]);
            *(short8*)(dst + i) = o;
        }
    }
}

// ---------------------------------------------------------------------------
// GEMM core, register-prefetch pipeline. C[m,n] = sum_k A[m,k]*B[n,k].
// Tile: MROWS x 128, BK=64, K=1024. 4 waves (2x2). XOR chunk swizzle.
// ---------------------------------------------------------------------------
template<int MROWS>
__device__ __forceinline__ void gemm_core_regpf(
    const short* __restrict__ A, const short* __restrict__ B,
    short* SM, int mbase, int nbase, f32x4 (*acc)[4])
{
    constexpr int TA = MROWS / 32;
    short* As = SM;
    short* Bs = SM + MROWS * 64;

    const int tid = threadIdx.x;
    const int wave = tid >> 6, lane = tid & 63;
    const int wm = wave >> 1, wn = wave & 1;
    const int lr = lane & 15;
    const int srow = lane >> 3, jcl = lane & 7;

    #pragma unroll
    for (int a = 0; a < TA; ++a)
        #pragma unroll
        for (int b = 0; b < 4; ++b) acc[a][b] = (f32x4){0, 0, 0, 0};

    short8 an[TA], bn[4];
    #pragma unroll
    for (int t = 0; t < TA; ++t) {
        int w = wave * TA + t, r = w * 8 + srow, jc = jcl ^ (r & 7);
        an[t] = *(const short8*)&A[(size_t)(mbase + r) * TD + jc * 8];
    }
    #pragma unroll
    for (int t = 0; t < 4; ++t) {
        int w = wave * 4 + t, r = w * 8 + srow, jc = jcl ^ (r & 7);
        bn[t] = *(const short8*)&B[(size_t)(nbase + r) * TD + jc * 8];
    }
    #pragma unroll
    for (int t = 0; t < TA; ++t) *(short8*)&As[(wave * TA + t) * 512 + lane * 8] = an[t];
    #pragma unroll
    for (int t = 0; t < 4; ++t)  *(short8*)&Bs[(wave * 4 + t) * 512 + lane * 8] = bn[t];
    __syncthreads();

    for (int k0 = 0; k0 < TD; k0 += 64) {
        const bool more = (k0 + 64) < TD;
        if (more) {
            #pragma unroll
            for (int t = 0; t < TA; ++t) {
                int w = wave * TA + t, r = w * 8 + srow, jc = jcl ^ (r & 7);
                an[t] = *(const short8*)&A[(size_t)(mbase + r) * TD + k0 + 64 + jc * 8];
            }
            #pragma unroll
            for (int t = 0; t < 4; ++t) {
                int w = wave * 4 + t, r = w * 8 + srow, jc = jcl ^ (r & 7);
                bn[t] = *(const short8*)&B[(size_t)(nbase + r) * TD + k0 + 64 + jc * 8];
            }
        }
        #pragma unroll
        for (int kk = 0; kk < 64; kk += 32) {
            const int cc = (kk >> 3) + (lane >> 4);
            const int csw = (cc ^ (lr & 7)) << 3;
            short8 af[TA], bf[4];
            #pragma unroll
            for (int a = 0; a < TA; ++a)
                af[a] = *(const short8*)&As[(wm * (MROWS / 2) + a * 16 + lr) * 64 + csw];
            #pragma unroll
            for (int b = 0; b < 4; ++b)
                bf[b] = *(const short8*)&Bs[(wn * 64 + b * 16 + lr) * 64 + csw];
            #pragma unroll
            for (int a = 0; a < TA; ++a)
                #pragma unroll
                for (int b = 0; b < 4; ++b)
                    acc[a][b] = __builtin_amdgcn_mfma_f32_16x16x32_bf16(af[a], bf[b], acc[a][b], 0, 0, 0);
        }
        __syncthreads();
        if (more) {
            #pragma unroll
            for (int t = 0; t < TA; ++t) *(short8*)&As[(wave * TA + t) * 512 + lane * 8] = an[t];
            #pragma unroll
            for (int t = 0; t < 4; ++t)  *(short8*)&Bs[(wave * 4 + t) * 512 + lane * 8] = bn[t];
            __syncthreads();
        }
    }
}

// ---------------------------------------------------------------------------
// QKV projection; 128x128 tiles, grid (32, 8, 3).
// Q,K out [B,H,T,64] via LDS-transposed coalesced epilogue; V out [B,H,64,T].
// ---------------------------------------------------------------------------
__global__ __launch_bounds__(256, 3) void qkv_gemm_kernel(
    const short* __restrict__ x,
    const short* __restrict__ Wq, const short* __restrict__ Wk,
    const short* __restrict__ Wv,
    short* __restrict__ Qo, short* __restrict__ Ko, short* __restrict__ Vo)
{
    const short* W = (blockIdx.z == 0) ? Wq : (blockIdx.z == 1) ? Wk : Wv;
    short* Out = (blockIdx.z == 0) ? Qo : (blockIdx.z == 1) ? Ko : Vo;
    const bool transposeV = (blockIdx.z == 2);

    __shared__ __align__(16) short SM[128 * 64 * 2];

    const int mbase = blockIdx.x * 128, nbase = blockIdx.y * 128;
    f32x4 acc[4][4];
    gemm_core_regpf<128>(x, W, SM, mbase, nbase, acc);

    const int tid = threadIdx.x;
    const int wave = tid >> 6, lane = tid & 63;
    const int wm = wave >> 1, wn = wave & 1;
    const int lr = lane & 15;
    const int g4 = (lane >> 4) * 4;

    if (transposeV) {
        #pragma unroll
        for (int a = 0; a < 4; ++a) {
            #pragma unroll
            for (int b = 0; b < 4; ++b) {
                int m0 = mbase + wm * 64 + a * 16 + g4;
                int n = nbase + wn * 64 + b * 16 + lr;
                int bb = m0 >> 11, t0 = m0 & (TT - 1);
                int h = n >> 6, hd = n & 63;
                ushort4v pk;
                #pragma unroll
                for (int i = 0; i < 4; ++i) pk[i] = (unsigned short)f2bf(acc[a][b][i]);
                *(ushort4v*)&Out[((size_t)(bb * TH + h) * 64 + hd) * TT + t0] = pk;
            }
        }
    } else {
        short* Cs = SM;
        #pragma unroll
        for (int p = 0; p < 2; ++p) {
            __syncthreads();
            if (wn == p) {
                #pragma unroll
                for (int a = 0; a < 4; ++a)
                    #pragma unroll
                    for (int b = 0; b < 4; ++b)
                        #pragma unroll
                        for (int i = 0; i < 4; ++i) {
                            int ml = wm * 64 + a * 16 + g4 + i;
                            int nl = b * 16 + lr;
                            Cs[ml * 72 + nl] = f2bf(acc[a][b][i]);
                        }
            }
            __syncthreads();
            int tl = tid >> 1, hc = (tid & 1) * 32;
            int h = (nbase >> 6) + p;
            int m = mbase + tl;
            int bb = m >> 11, t = m & (TT - 1);
            size_t base = (((size_t)(bb * TH + h) * TT + t) << 6) + hc;
            #pragma unroll
            for (int q = 0; q < 4; ++q)
                *(short8*)&Out[base + q * 8] = *(short8*)&Cs[tl * 72 + hc + q * 8];
        }
    }
}

// ---------------------------------------------------------------------------
// Output projection; 64x128 tiles, grid (64, 8).
// ---------------------------------------------------------------------------
__global__ __launch_bounds__(256, 2) void out_gemm_kernel(
    const short* __restrict__ A, const short* __restrict__ W,
    void* __restrict__ C, const unsigned short* __restrict__ xq)
{
    const int f = detect_bf16(xq);

    __shared__ __align__(16) short SM[64 * 64 + 128 * 64];

    const int mbase = blockIdx.x * 64, nbase = blockIdx.y * 128;
    f32x4 acc[2][4];
    gemm_core_regpf<64>(A, W, SM, mbase, nbase, acc);

    const int tid = threadIdx.x;
    const int wave = tid >> 6, lane = tid & 63;
    const int wm = wave >> 1, wn = wave & 1;
    const int lr = lane & 15;
    const int g4 = (lane >> 4) * 4;

    #pragma unroll
    for (int a = 0; a < 2; ++a) {
        #pragma unroll
        for (int b = 0; b < 4; ++b) {
            #pragma unroll
            for (int i = 0; i < 4; ++i) {
                int m = mbase + wm * 32 + a * 16 + g4 + i;
                int n = nbase + wn * 64 + b * 16 + lr;
                if (f) ((short*)C)[(size_t)m * TD + n] = f2bf(acc[a][b][i]);
                else   ((float*)C)[(size_t)m * TD + n] = acc[a][b][i];
            }
        }
    }
}

// ---------------------------------------------------------------------------
// Split-S flash attention. grid (32 bh, 64 work), block 256, 64 q-rows.
// work j -> snake-dealt (qtile, half); each half covers part of the k-range
// and writes unnormalized partial O (bf16) + m,l (fp32). CU-classes (j&7)
// have near-equal tile sums and share one bh (L2 locality).
// ---------------------------------------------------------------------------
__global__ __launch_bounds__(256) void attn_split_kernel(
    const short* __restrict__ Q, const short* __restrict__ K,
    const short* __restrict__ V, short* __restrict__ Opart,
    float* __restrict__ mbuf, float* __restrict__ lbuf)
{
    const int j = blockIdx.y;
    const int rd = j >> 3, cd = j & 7;
    const int idx = rd * 8 + ((rd & 1) ? (7 - cd) : cd);   // snake over desc cost
    const int qt = 31 - (idx >> 1);
    const int half = idx & 1;
    const int bh = blockIdx.x;

    const int nt = qt + 1, nt0 = (qt + 2) >> 1;
    const int tb = half ? nt0 : 0;     // tile range [tb, te)
    const int te = half ? nt : nt0;

    const int tid = threadIdx.x;
    const size_t pslot = (size_t)(half * 32 + bh) * 32 + qt;
    float* mrow = mbuf + pslot * 64;
    float* lrow = lbuf + pslot * 64;

    if (tb >= te) { // empty half: mark so merge weights it to zero
        if (tid < 64) mrow[tid] = NEG_BIG;
        return;
    }

    const int qbase = qt * 64;
    const short* Qp = Q + (size_t)bh * TT * 64;
    const short* Kp = K + (size_t)bh * TT * 64;
    const short* Vp = V + (size_t)bh * 64 * TT;   // V^T: [64][TT]

    __shared__ __align__(16) short Ks[64][72];
    __shared__ __align__(16) short Vt[64][72];
    __shared__ __align__(16) short Ps[4][16][72];

    const int wave = tid >> 6, lane = tid & 63;
    const int lr = lane & 15;
    const int lk = (lane >> 4) * 8;
    const int g4 = (lane >> 4) * 4;

    const int r0 = tid >> 3, c0 = (tid & 7) * 8;
    const int r1 = (tid + 256) >> 3, c1 = c0;

    const int qrowA = qbase + wave * 16 + lr;
    const short8 qf0 = *(const short8*)&Qp[(size_t)qrowA * 64 + lk];
    const short8 qf1 = *(const short8*)&Qp[(size_t)qrowA * 64 + 32 + lk];

    f32x4 Oa[4] = {{0,0,0,0},{0,0,0,0},{0,0,0,0},{0,0,0,0}};
    float m_i = NEG_BIG, l_i = 0.f;

    const int kb64 = tb * 64, ke64 = te * 64;
    {
        short8 ka = *(const short8*)&Kp[(size_t)(kb64 + r0) * 64 + c0];
        short8 kb = *(const short8*)&Kp[(size_t)(kb64 + r1) * 64 + c1];
        short8 va = *(const short8*)&Vp[(size_t)r0 * TT + kb64 + c0];
        short8 vb = *(const short8*)&Vp[(size_t)r1 * TT + kb64 + c1];
        *(short8*)&Ks[r0][c0] = ka;
        *(short8*)&Ks[r1][c1] = kb;
        *(short8*)&Vt[r0][c0] = va;
        *(short8*)&Vt[r1][c1] = vb;
    }
    __syncthreads();

    for (int kt = kb64; kt < ke64; kt += 64) {
        const bool more = (kt + 64) < ke64;
        short8 ka, kb, va, vb;
        if (more) {
            const int kn = kt + 64;
            ka = *(const short8*)&Kp[(size_t)(kn + r0) * 64 + c0];
            kb = *(const short8*)&Kp[(size_t)(kn + r1) * 64 + c1];
            va = *(const short8*)&Vp[(size_t)r0 * TT + kn + c0];
            vb = *(const short8*)&Vp[(size_t)r1 * TT + kn + c1];
        }

        f32x4 s[4];
        #pragma unroll
        for (int c = 0; c < 4; ++c) {
            f32x4 z = {0, 0, 0, 0};
            short8 k0v = *(const short8*)&Ks[c * 16 + lr][lk];
            short8 k1v = *(const short8*)&Ks[c * 16 + lr][32 + lk];
            z = __builtin_amdgcn_mfma_f32_16x16x32_bf16(k0v, qf0, z, 0, 0, 0);
            z = __builtin_amdgcn_mfma_f32_16x16x32_bf16(k1v, qf1, z, 0, 0, 0);
            s[c] = z;
        }

        const bool diag = (kt == qbase);
        #pragma unroll
        for (int c = 0; c < 4; ++c) {
            #pragma unroll
            for (int i = 0; i < 4; ++i) {
                float v = s[c][i] * SCALE_LOG2;
                if (diag) {
                    int colg = kt + c * 16 + g4 + i;
                    if (colg > qrowA) v = NEG_BIG;
                }
                s[c][i] = v;
            }
        }

        float vmax = s[0][0];
        #pragma unroll
        for (int c = 0; c < 4; ++c)
            #pragma unroll
            for (int i = 0; i < 4; ++i) vmax = fmaxf(vmax, s[c][i]);
        vmax = fmaxf(vmax, __shfl_xor(vmax, 16, 64));
        vmax = fmaxf(vmax, __shfl_xor(vmax, 32, 64));
        float mnew = fmaxf(m_i, vmax);
        float alpha = fast_exp2(m_i - mnew);
        m_i = mnew;

        float rsum = 0.f;
        #pragma unroll
        for (int c = 0; c < 4; ++c) {
            ushort4v pk;
            #pragma unroll
            for (int i = 0; i < 4; ++i) {
                float p = fast_exp2(s[c][i] - mnew);
                rsum += p;
                pk[i] = (unsigned short)f2bf(p);
            }
            *(ushort4v*)&Ps[wave][lr][c * 16 + g4] = pk;
        }
        rsum += __shfl_xor(rsum, 16, 64);
        rsum += __shfl_xor(rsum, 32, 64);
        l_i = l_i * alpha + rsum;

        float ab[4];
        #pragma unroll
        for (int i = 0; i < 4; ++i) ab[i] = __shfl(alpha, g4 + i, 64);
        #pragma unroll
        for (int c = 0; c < 4; ++c)
            #pragma unroll
            for (int i = 0; i < 4; ++i) Oa[c][i] *= ab[i];

        // no barrier: Ps[wave] is wave-private, same-wave DS ops ordered
        #pragma unroll
        for (int kk = 0; kk < 2; ++kk) {
            short8 af = *(const short8*)&Ps[wave][lr][kk * 32 + lk];
            #pragma unroll
            for (int c = 0; c < 4; ++c) {
                short8 bf = *(const short8*)&Vt[c * 16 + lr][kk * 32 + lk];
                Oa[c] = __builtin_amdgcn_mfma_f32_16x16x32_bf16(af, bf, Oa[c], 0, 0, 0);
            }
        }
        __syncthreads();

        if (more) {
            *(short8*)&Ks[r0][c0] = ka;
            *(short8*)&Ks[r1][c1] = kb;
            *(short8*)&Vt[r0][c0] = va;
            *(short8*)&Vt[r1][c1] = vb;
            __syncthreads();
        }
    }

    // epilogue: unnormalized partial O + per-row m,l
    short* Ob = (short*)Opart + pslot * 4096;
    #pragma unroll
    for (int c = 0; c < 4; ++c) {
        #pragma unroll
        for (int i = 0; i < 4; ++i) {
            int rloc = wave * 16 + g4 + i;
            Ob[rloc * 64 + c * 16 + lr] = f2bf(Oa[c][i]);
        }
    }
    if (lane < 16) {
        mrow[wave * 16 + lr] = m_i;
        lrow[wave * 16 + lr] = l_i;
    }
}

// ---------------------------------------------------------------------------
// Merge the two halves: O = (w0*O0 + w1*O1) / (w0*l0 + w1*l1), write Ab.
// grid (32 bh, 32 qt), 256 threads; thread -> (row, 16-col group).
// ---------------------------------------------------------------------------
__global__ __launch_bounds__(256) void attn_merge_kernel(
    const short* __restrict__ Opart, const float* __restrict__ mbuf,
    const float* __restrict__ lbuf, short* __restrict__ AO)
{
    const int bh = blockIdx.x, qt = blockIdx.y;
    const int b = bh >> 4, h = bh & 15;
    const int t = threadIdx.x;
    const int r = t >> 2, cb = (t & 3) * 16;

    const size_t s0 = (size_t)bh * 32 + qt;
    const size_t s1 = (size_t)(32 + bh) * 32 + qt;
    float m0 = mbuf[s0 * 64 + r], m1 = mbuf[s1 * 64 + r];
    float l0 = lbuf[s0 * 64 + r], l1 = lbuf[s1 * 64 + r];
    float m = fmaxf(m0, m1);
    float w0 = fast_exp2(m0 - m), w1 = fast_exp2(m1 - m);
    float inv = 1.0f / (w0 * l0 + w1 * l1);
    w0 *= inv; w1 *= inv;

    const size_t o0 = s0 * 4096 + r * 64 + cb;
    const size_t o1 = s1 * 4096 + r * 64 + cb;
    short8 va0 = *(const short8*)&Opart[o0], vb0 = *(const short8*)&Opart[o0 + 8];
    short8 va1 = *(const short8*)&Opart[o1], vb1 = *(const short8*)&Opart[o1 + 8];
    short8 oa, ob;
    #pragma unroll
    for (int i = 0; i < 8; ++i) {
        oa[i] = f2bf(w0 * bf2f(va0[i]) + w1 * bf2f(va1[i]));
        ob[i] = f2bf(w0 * bf2f(vb0[i]) + w1 * bf2f(vb1[i]));
    }
    size_t ab = ((size_t)(b * TT + qt * 64 + r) << 10) + h * 64 + cb;
    *(short8*)&AO[ab] = oa;
    *(short8*)&AO[ab + 8] = ob;
}

// ---------------------------------------------------------------------------
// Fallback single-pass attention (R9) for small ws. grid (32 bh, 32 q_ord).
// ---------------------------------------------------------------------------
__global__ __launch_bounds__(256) void attn_kernel(
    const short* __restrict__ Q, const short* __restrict__ K,
    const short* __restrict__ V, short* __restrict__ AO)
{
    const int j = blockIdx.y, cdeal = j & 7, rdeal = j >> 3;
    const int qtile = (rdeal == 0) ? 31 - cdeal :
                      (rdeal == 1) ? 16 + cdeal :
                      (rdeal == 2) ? 15 - cdeal : cdeal;
    const int bh = blockIdx.x;
    const int qbase = qtile * 64;
    const short* Qp = Q + (size_t)bh * TT * 64;
    const short* Kp = K + (size_t)bh * TT * 64;
    const short* Vp = V + (size_t)bh * 64 * TT;

    __shared__ __align__(16) short Ks[64][72];
    __shared__ __align__(16) short Vt[64][72];
    __shared__ __align__(16) short Ps[4][16][72];

    const int tid = threadIdx.x;
    const int wave = tid >> 6, lane = tid & 63;
    const int lr = lane & 15;
    const int lk = (lane >> 4) * 8;
    const int g4 = (lane >> 4) * 4;
    const int b = bh >> 4, h = bh & 15;

    const int r0 = tid >> 3, c0 = (tid & 7) * 8;
    const int r1 = (tid + 256) >> 3, c1 = c0;

    const int qrowA = qbase + wave * 16 + lr;
    const short8 qf0 = *(const short8*)&Qp[(size_t)qrowA * 64 + lk];
    const short8 qf1 = *(const short8*)&Qp[(size_t)qrowA * 64 + 32 + lk];

    f32x4 Oa[4] = {{0,0,0,0},{0,0,0,0},{0,0,0,0},{0,0,0,0}};
    float m_i = NEG_BIG, l_i = 0.f;

    {
        short8 ka = *(const short8*)&Kp[(size_t)r0 * 64 + c0];
        short8 kb = *(const short8*)&Kp[(size_t)r1 * 64 + c1];
        short8 va = *(const short8*)&Vp[(size_t)r0 * TT + c0];
        short8 vb = *(const short8*)&Vp[(size_t)r1 * TT + c1];
        *(short8*)&Ks[r0][c0] = ka;
        *(short8*)&Ks[r1][c1] = kb;
        *(short8*)&Vt[r0][c0] = va;
        *(short8*)&Vt[r1][c1] = vb;
    }
    __syncthreads();

    const int kend = qbase + 64;
    for (int kt = 0; kt < kend; kt += 64) {
        const bool more = (kt + 64) < kend;
        short8 ka, kb, va, vb;
        if (more) {
            const int kn = kt + 64;
            ka = *(const short8*)&Kp[(size_t)(kn + r0) * 64 + c0];
            kb = *(const short8*)&Kp[(size_t)(kn + r1) * 64 + c1];
            va = *(const short8*)&Vp[(size_t)r0 * TT + kn + c0];
            vb = *(const short8*)&Vp[(size_t)r1 * TT + kn + c1];
        }

        f32x4 s[4];
        #pragma unroll
        for (int c = 0; c < 4; ++c) {
            f32x4 z = {0, 0, 0, 0};
            short8 k0v = *(const short8*)&Ks[c * 16 + lr][lk];
            short8 k1v = *(const short8*)&Ks[c * 16 + lr][32 + lk];
            z = __builtin_amdgcn_mfma_f32_16x16x32_bf16(k0v, qf0, z, 0, 0, 0);
            z = __builtin_amdgcn_mfma_f32_16x16x32_bf16(k1v, qf1, z, 0, 0, 0);
            s[c] = z;
        }

        const bool diag = (kt == qbase);
        #pragma unroll
        for (int c = 0; c < 4; ++c) {
            #pragma unroll
            for (int i = 0; i < 4; ++i) {
                float v = s[c][i] * SCALE_LOG2;
                if (diag) {
                    int colg = kt + c * 16 + g4 + i;
                    if (colg > qrowA) v = NEG_BIG;
                }
                s[c][i] = v;
            }
        }

        float vmax = s[0][0];
        #pragma unroll
        for (int c = 0; c < 4; ++c)
            #pragma unroll
            for (int i = 0; i < 4; ++i) vmax = fmaxf(vmax, s[c][i]);
        vmax = fmaxf(vmax, __shfl_xor(vmax, 16, 64));
        vmax = fmaxf(vmax, __shfl_xor(vmax, 32, 64));
        float mnew = fmaxf(m_i, vmax);
        float alpha = fast_exp2(m_i - mnew);
        m_i = mnew;

        float rsum = 0.f;
        #pragma unroll
        for (int c = 0; c < 4; ++c) {
            ushort4v pk;
            #pragma unroll
            for (int i = 0; i < 4; ++i) {
                float p = fast_exp2(s[c][i] - mnew);
                rsum += p;
                pk[i] = (unsigned short)f2bf(p);
            }
            *(ushort4v*)&Ps[wave][lr][c * 16 + g4] = pk;
        }
        rsum += __shfl_xor(rsum, 16, 64);
        rsum += __shfl_xor(rsum, 32, 64);
        l_i = l_i * alpha + rsum;

        float ab[4];
        #pragma unroll
        for (int i = 0; i < 4; ++i) ab[i] = __shfl(alpha, g4 + i, 64);
        #pragma unroll
        for (int c = 0; c < 4; ++c)
            #pragma unroll
            for (int i = 0; i < 4; ++i) Oa[c][i] *= ab[i];

        #pragma unroll
        for (int kk = 0; kk < 2; ++kk) {
            short8 af = *(const short8*)&Ps[wave][lr][kk * 32 + lk];
            #pragma unroll
            for (int c = 0; c < 4; ++c) {
                short8 bf = *(const short8*)&Vt[c * 16 + lr][kk * 32 + lk];
                Oa[c] = __builtin_amdgcn_mfma_f32_16x16x32_bf16(af, bf, Oa[c], 0, 0, 0);
            }
        }
        __syncthreads();

        if (more) {
            *(short8*)&Ks[r0][c0] = ka;
            *(short8*)&Ks[r1][c1] = kb;
            *(short8*)&Vt[r0][c0] = va;
            *(short8*)&Vt[r1][c1] = vb;
            __syncthreads();
        }
    }

    float lb[4];
    #pragma unroll
    for (int i = 0; i < 4; ++i) lb[i] = 1.0f / __shfl(l_i, g4 + i, 64);
    #pragma unroll
    for (int c = 0; c < 4; ++c) {
        #pragma unroll
        for (int i = 0; i < 4; ++i) {
            int qr = qbase + wave * 16 + g4 + i;
            float v = Oa[c][i] * lb[i];
            AO[((size_t)(b * TT + qr) << 10) + h * 64 + c * 16 + lr] = f2bf(v);
        }
    }
}

// ---------------------------------------------------------------------------
extern "C" void kernel_launch(void* const* d_in, const int* in_sizes, int n_in,
                              void* d_out, int out_size, void* d_ws, size_t ws_size,
                              hipStream_t stream)
{
    char* ws = (char*)d_ws;
    const size_t XB  = (size_t)TM * TD * 2;   // 8 MiB bf16 x
    const size_t WB  = (size_t)TD * TD * 2;   // 2 MiB bf16 weight
    const size_t BUF = (size_t)TM * TD * 2;   // 8 MiB activation

    short* xb  = (short*)(ws + 256);
    short* Wqb = (short*)(ws + 256 + XB);
    short* Wkb = (short*)(ws + 256 + XB + WB);
    short* Wvb = (short*)(ws + 256 + XB + 2 * WB);
    short* Wob = (short*)(ws + 256 + XB + 3 * WB);
    char*  act = ws + 256 + XB + 4 * WB;
    short* Qb = (short*)(act);
    short* Kb = (short*)(act + BUF);
    short* Vb = (short*)(act + 2 * BUF);   // V^T [B,H,64,T]
    short* Ab = (short*)(act + 3 * BUF);
    char*  part = act + 4 * BUF;
    short* Opart = (short*)part;                            // 16 MiB
    float* mbuf  = (float*)(part + (size_t)16 * 1024 * 1024);      // 512 KiB
    float* lbuf  = (float*)(part + (size_t)16 * 1024 * 1024 + 524288);

    const size_t need = 256 + XB + 4 * WB + 4 * BUF +
                        (size_t)16 * 1024 * 1024 + 2 * 524288;
    const bool splitS = (ws_size >= need);   // constant across calls: graph-safe

    dim3 blk(256);
    convert_all_kernel<<<dim3(512 + 4 * 128), blk, 0, stream>>>(
        d_in[0], d_in[1], d_in[2], d_in[3], d_in[4], xb, Wqb, Wkb, Wvb, Wob);
    qkv_gemm_kernel<<<dim3(TM / 128, TD / 128, 3), blk, 0, stream>>>(xb, Wqb, Wkb, Wvb, Qb, Kb, Vb);
    if (splitS) {
        attn_split_kernel<<<dim3(32, 64), blk, 0, stream>>>(Qb, Kb, Vb, Opart, mbuf, lbuf);
        attn_merge_kernel<<<dim3(32, 32), blk, 0, stream>>>(Opart, mbuf, lbuf, Ab);
    } else {
        attn_kernel<<<dim3(32, 32), blk, 0, stream>>>(Qb, Kb, Vb, Ab);
    }
    out_gemm_kernel<<<dim3(TM / 64, TD / 128), blk, 0, stream>>>(
        Ab, Wob, d_out, (const unsigned short*)d_in[0]);
}

// Round 11
// 187.944 us; speedup vs baseline: 1.6759x; 1.0056x over previous
//
#include <hip/hip_runtime.h>
#include <hip/hip_bf16.h>

// Problem: B=2, T=2048, D=1024, H=16, HD=64.
// Runtime-detect fp32 vs bf16 inputs (inline, per-wave); canonicalize to bf16.
// convert_all -> qkv gemm (Q,K via swapped operands -> packed stores;
// V:[B,H,64,T]) -> split-S flash attention with FIXED-SHIFT softmax
// (P = exp2(S*scale - 16), exact; partials directly summable) -> merge ->
// out gemm (64x128).

#define TB 2
#define TT 2048
#define TD 1024
#define TH 16
#define TM (TB * TT) // 4096

#define NEG_BIG (-1e30f)
#define SCALE_LOG2 0.18033688f  // (1/sqrt(64)) * log2(e)
#define FSHIFT 16.0f            // fixed softmax shift (exact; cancels in O/l)

typedef __attribute__((ext_vector_type(8))) short short8;
typedef __attribute__((ext_vector_type(4))) float f32x4;
typedef __attribute__((ext_vector_type(4))) unsigned short ushort4v;

__device__ __forceinline__ short f2bf(float f) {
    __hip_bfloat16 h = __float2bfloat16(f);
    return __builtin_bit_cast(short, h);
}

__device__ __forceinline__ float bf2f(short u) {
    unsigned int x = ((unsigned int)(unsigned short)u) << 16;
    return __builtin_bit_cast(float, x);
}

__device__ __forceinline__ float fast_exp2(float x) {
#if __has_builtin(__builtin_amdgcn_exp2f)
    return __builtin_amdgcn_exp2f(x);
#else
    return exp2f(x);
#endif
}

// Inline dtype detect: sample even u16s of x; uniform per wave.
__device__ __forceinline__ int detect_bf16(const unsigned short* xq) {
    int lane = threadIdx.x & 63;
    unsigned short u = xq[lane * 2];
    int e = (u >> 7) & 0xFF;
    int sane = ((e >= 100 && e <= 145) || u == 0) ? 1 : 0;
    unsigned long long b = __ballot(sane);
    return (__popcll(b) >= 48) ? 1 : 0; // 1 = bf16, 0 = fp32
}

// ---------------------------------------------------------------------------
// One dispatch converts x + 4 weights; 8192 elems/block.
// ---------------------------------------------------------------------------
__global__ __launch_bounds__(256) void convert_all_kernel(
    const void* __restrict__ x,  const void* __restrict__ wq,
    const void* __restrict__ wk, const void* __restrict__ wv,
    const void* __restrict__ wo,
    short* __restrict__ xb, short* __restrict__ wqb, short* __restrict__ wkb,
    short* __restrict__ wvb, short* __restrict__ wob)
{
    const int f = detect_bf16((const unsigned short*)x);
    int bid = blockIdx.x;
    const void* src; short* dst; int base;
    if (bid < 512) { src = x; dst = xb; base = bid; }
    else {
        int w = (bid - 512) >> 7, lb = (bid - 512) & 127;
        src = (w == 0) ? wq : (w == 1) ? wk : (w == 2) ? wv : wo;
        dst = (w == 0) ? wqb : (w == 1) ? wkb : (w == 2) ? wvb : wob;
        base = lb;
    }
    int i0 = base * 8192 + (int)threadIdx.x * 8;
    #pragma unroll
    for (int r = 0; r < 4; ++r) {
        int i = i0 + r * 2048;
        if (f) {
            *(short8*)(dst + i) = *(const short8*)((const short*)src + i);
        } else {
            const float* s = (const float*)src + i;
            short8 o;
            #pragma unroll
            for (int j = 0; j < 8; ++j) o[j] = f2bf(s[j]);
            *(short8*)(dst + i) = o;
        }
    }
}

// ---------------------------------------------------------------------------
// GEMM core, register-prefetch pipeline. C[m,n] = sum_k A[m,k]*B[n,k].
// Tile: MROWS x 128, BK=64, K=1024. 4 waves (2x2). XOR chunk swizzle.
// ---------------------------------------------------------------------------
template<int MROWS>
__device__ __forceinline__ void gemm_core_regpf(
    const short* __restrict__ A, const short* __restrict__ B,
    short* SM, int mbase, int nbase, f32x4 (*acc)[4])
{
    constexpr int TA = MROWS / 32;
    short* As = SM;
    short* Bs = SM + MROWS * 64;

    const int tid = threadIdx.x;
    const int wave = tid >> 6, lane = tid & 63;
    const int wm = wave >> 1, wn = wave & 1;
    const int lr = lane & 15;
    const int srow = lane >> 3, jcl = lane & 7;

    #pragma unroll
    for (int a = 0; a < TA; ++a)
        #pragma unroll
        for (int b = 0; b < 4; ++b) acc[a][b] = (f32x4){0, 0, 0, 0};

    short8 an[TA], bn[4];
    #pragma unroll
    for (int t = 0; t < TA; ++t) {
        int w = wave * TA + t, r = w * 8 + srow, jc = jcl ^ (r & 7);
        an[t] = *(const short8*)&A[(size_t)(mbase + r) * TD + jc * 8];
    }
    #pragma unroll
    for (int t = 0; t < 4; ++t) {
        int w = wave * 4 + t, r = w * 8 + srow, jc = jcl ^ (r & 7);
        bn[t] = *(const short8*)&B[(size_t)(nbase + r) * TD + jc * 8];
    }
    #pragma unroll
    for (int t = 0; t < TA; ++t) *(short8*)&As[(wave * TA + t) * 512 + lane * 8] = an[t];
    #pragma unroll
    for (int t = 0; t < 4; ++t)  *(short8*)&Bs[(wave * 4 + t) * 512 + lane * 8] = bn[t];
    __syncthreads();

    for (int k0 = 0; k0 < TD; k0 += 64) {
        const bool more = (k0 + 64) < TD;
        if (more) {
            #pragma unroll
            for (int t = 0; t < TA; ++t) {
                int w = wave * TA + t, r = w * 8 + srow, jc = jcl ^ (r & 7);
                an[t] = *(const short8*)&A[(size_t)(mbase + r) * TD + k0 + 64 + jc * 8];
            }
            #pragma unroll
            for (int t = 0; t < 4; ++t) {
                int w = wave * 4 + t, r = w * 8 + srow, jc = jcl ^ (r & 7);
                bn[t] = *(const short8*)&B[(size_t)(nbase + r) * TD + k0 + 64 + jc * 8];
            }
        }
        #pragma unroll
        for (int kk = 0; kk < 64; kk += 32) {
            const int cc = (kk >> 3) + (lane >> 4);
            const int csw = (cc ^ (lr & 7)) << 3;
            short8 af[TA], bf[4];
            #pragma unroll
            for (int a = 0; a < TA; ++a)
                af[a] = *(const short8*)&As[(wm * (MROWS / 2) + a * 16 + lr) * 64 + csw];
            #pragma unroll
            for (int b = 0; b < 4; ++b)
                bf[b] = *(const short8*)&Bs[(wn * 64 + b * 16 + lr) * 64 + csw];
            #pragma unroll
            for (int a = 0; a < TA; ++a)
                #pragma unroll
                for (int b = 0; b < 4; ++b)
                    acc[a][b] = __builtin_amdgcn_mfma_f32_16x16x32_bf16(af[a], bf[b], acc[a][b], 0, 0, 0);
        }
        __syncthreads();
        if (more) {
            #pragma unroll
            for (int t = 0; t < TA; ++t) *(short8*)&As[(wave * TA + t) * 512 + lane * 8] = an[t];
            #pragma unroll
            for (int t = 0; t < 4; ++t)  *(short8*)&Bs[(wave * 4 + t) * 512 + lane * 8] = bn[t];
            __syncthreads();
        }
    }
}

// ---------------------------------------------------------------------------
// QKV projection; grid (32, 8, 3).
// Q,K (z=0,1): SWAPPED operands (A=W over D, B=x over tokens) so each lane's
// 4 acc values are 4 consecutive hd for one token -> packed 8B stores, no
// LDS transpose. V (z=2): A=x, B=W; out transposed [B,H,64,T], packed 8B.
// ---------------------------------------------------------------------------
__global__ __launch_bounds__(256, 3) void qkv_gemm_kernel(
    const short* __restrict__ x,
    const short* __restrict__ Wq, const short* __restrict__ Wk,
    const short* __restrict__ Wv,
    short* __restrict__ Qo, short* __restrict__ Ko, short* __restrict__ Vo)
{
    const short* W = (blockIdx.z == 0) ? Wq : (blockIdx.z == 1) ? Wk : Wv;
    short* Out = (blockIdx.z == 0) ? Qo : (blockIdx.z == 1) ? Ko : Vo;
    const bool transposeV = (blockIdx.z == 2);

    __shared__ __align__(16) short SM[128 * 64 * 2];

    f32x4 acc[4][4];
    const int tid = threadIdx.x;
    const int wave = tid >> 6, lane = tid & 63;
    const int wm = wave >> 1, wn = wave & 1;
    const int lr = lane & 15;
    const int g4 = (lane >> 4) * 4;

    if (!transposeV) {
        // A = W (m over D), B = x (n over tokens)
        const int mbase = blockIdx.y * 128, nbase = blockIdx.x * 128;
        gemm_core_regpf<128>(W, x, SM, mbase, nbase, acc);
        #pragma unroll
        for (int a = 0; a < 4; ++a) {
            #pragma unroll
            for (int b = 0; b < 4; ++b) {
                int d0 = mbase + wm * 64 + a * 16 + g4;   // 4 consecutive hd
                int n = nbase + wn * 64 + b * 16 + lr;    // token
                int bb = n >> 11, t = n & (TT - 1);
                int h = d0 >> 6, hd = d0 & 63;
                ushort4v pk;
                #pragma unroll
                for (int i = 0; i < 4; ++i) pk[i] = (unsigned short)f2bf(acc[a][b][i]);
                *(ushort4v*)&Out[(((size_t)(bb * TH + h) * TT + t) << 6) + hd] = pk;
            }
        }
    } else {
        // A = x (m over tokens), B = W (n over D); V^T out [B,H,64,T]
        const int mbase = blockIdx.x * 128, nbase = blockIdx.y * 128;
        gemm_core_regpf<128>(x, W, SM, mbase, nbase, acc);
        #pragma unroll
        for (int a = 0; a < 4; ++a) {
            #pragma unroll
            for (int b = 0; b < 4; ++b) {
                int m0 = mbase + wm * 64 + a * 16 + g4;   // 4 consecutive t
                int n = nbase + wn * 64 + b * 16 + lr;
                int bb = m0 >> 11, t0 = m0 & (TT - 1);
                int h = n >> 6, hd = n & 63;
                ushort4v pk;
                #pragma unroll
                for (int i = 0; i < 4; ++i) pk[i] = (unsigned short)f2bf(acc[a][b][i]);
                *(ushort4v*)&Out[((size_t)(bb * TH + h) * 64 + hd) * TT + t0] = pk;
            }
        }
    }
}

// ---------------------------------------------------------------------------
// Output projection; 64x128 tiles, grid (64, 8).
// ---------------------------------------------------------------------------
__global__ __launch_bounds__(256, 2) void out_gemm_kernel(
    const short* __restrict__ A, const short* __restrict__ W,
    void* __restrict__ C, const unsigned short* __restrict__ xq)
{
    const int f = detect_bf16(xq);

    __shared__ __align__(16) short SM[64 * 64 + 128 * 64];

    const int mbase = blockIdx.x * 64, nbase = blockIdx.y * 128;
    f32x4 acc[2][4];
    gemm_core_regpf<64>(A, W, SM, mbase, nbase, acc);

    const int tid = threadIdx.x;
    const int wave = tid >> 6, lane = tid & 63;
    const int wm = wave >> 1, wn = wave & 1;
    const int lr = lane & 15;
    const int g4 = (lane >> 4) * 4;

    #pragma unroll
    for (int a = 0; a < 2; ++a) {
        #pragma unroll
        for (int b = 0; b < 4; ++b) {
            #pragma unroll
            for (int i = 0; i < 4; ++i) {
                int m = mbase + wm * 32 + a * 16 + g4 + i;
                int n = nbase + wn * 64 + b * 16 + lr;
                if (f) ((short*)C)[(size_t)m * TD + n] = f2bf(acc[a][b][i]);
                else   ((float*)C)[(size_t)m * TD + n] = acc[a][b][i];
            }
        }
    }
}

// ---------------------------------------------------------------------------
// Split-S flash attention, FIXED-SHIFT softmax (exact; P = 2^(S*scale-16)).
// grid (32 bh, 64 work), block 256, 64 q-rows. Snake-dealt (qtile, half).
// Partial O (unnormalized, bf16) + l (fp32); partials directly summable.
// ---------------------------------------------------------------------------
__global__ __launch_bounds__(256) void attn_split_kernel(
    const short* __restrict__ Q, const short* __restrict__ K,
    const short* __restrict__ V, short* __restrict__ Opart,
    float* __restrict__ lbuf)
{
    const int j = blockIdx.y;
    const int rd = j >> 3, cd = j & 7;
    const int idx = rd * 8 + ((rd & 1) ? (7 - cd) : cd);
    const int qt = 31 - (idx >> 1);
    const int half = idx & 1;
    const int bh = blockIdx.x;

    const int nt = qt + 1, nt0 = (qt + 2) >> 1;
    const int tb = half ? nt0 : 0;
    const int te = half ? nt : nt0;

    const int tid = threadIdx.x;
    const size_t pslot = (size_t)(half * 32 + bh) * 32 + qt;
    float* lrow = lbuf + pslot * 64;
    short* Ob = Opart + pslot * 4096;

    if (tb >= te) { // empty half: zero contribution
        short8 z8 = {0, 0, 0, 0, 0, 0, 0, 0};
        *(short8*)&Ob[tid * 16] = z8;
        *(short8*)&Ob[tid * 16 + 8] = z8;
        if (tid < 64) lrow[tid] = 0.f;
        return;
    }

    const int qbase = qt * 64;
    const short* Qp = Q + (size_t)bh * TT * 64;
    const short* Kp = K + (size_t)bh * TT * 64;
    const short* Vp = V + (size_t)bh * 64 * TT;   // V^T: [64][TT]

    __shared__ __align__(16) short Ks[64][72];
    __shared__ __align__(16) short Vt[64][72];
    __shared__ __align__(16) short Ps[4][16][72];

    const int wave = tid >> 6, lane = tid & 63;
    const int lr = lane & 15;
    const int lk = (lane >> 4) * 8;
    const int g4 = (lane >> 4) * 4;

    const int r0 = tid >> 3, c0 = (tid & 7) * 8;
    const int r1 = (tid + 256) >> 3, c1 = c0;

    const int qrowA = qbase + wave * 16 + lr;
    const short8 qf0 = *(const short8*)&Qp[(size_t)qrowA * 64 + lk];
    const short8 qf1 = *(const short8*)&Qp[(size_t)qrowA * 64 + 32 + lk];

    f32x4 Oa[4] = {{0,0,0,0},{0,0,0,0},{0,0,0,0},{0,0,0,0}};
    float l_i = 0.f;   // in-lane partial (16 cols); cross-quad at epilogue

    const int kb64 = tb * 64, ke64 = te * 64;
    {
        short8 ka = *(const short8*)&Kp[(size_t)(kb64 + r0) * 64 + c0];
        short8 kb = *(const short8*)&Kp[(size_t)(kb64 + r1) * 64 + c1];
        short8 va = *(const short8*)&Vp[(size_t)r0 * TT + kb64 + c0];
        short8 vb = *(const short8*)&Vp[(size_t)r1 * TT + kb64 + c1];
        *(short8*)&Ks[r0][c0] = ka;
        *(short8*)&Ks[r1][c1] = kb;
        *(short8*)&Vt[r0][c0] = va;
        *(short8*)&Vt[r1][c1] = vb;
    }
    __syncthreads();

    for (int kt = kb64; kt < ke64; kt += 64) {
        const bool more = (kt + 64) < ke64;
        short8 ka, kb, va, vb;
        if (more) {
            const int kn = kt + 64;
            ka = *(const short8*)&Kp[(size_t)(kn + r0) * 64 + c0];
            kb = *(const short8*)&Kp[(size_t)(kn + r1) * 64 + c1];
            va = *(const short8*)&Vp[(size_t)r0 * TT + kn + c0];
            vb = *(const short8*)&Vp[(size_t)r1 * TT + kn + c1];
        }

        // S^T = K Q^T
        f32x4 s[4];
        #pragma unroll
        for (int c = 0; c < 4; ++c) {
            f32x4 z = {0, 0, 0, 0};
            short8 k0v = *(const short8*)&Ks[c * 16 + lr][lk];
            short8 k1v = *(const short8*)&Ks[c * 16 + lr][32 + lk];
            z = __builtin_amdgcn_mfma_f32_16x16x32_bf16(k0v, qf0, z, 0, 0, 0);
            z = __builtin_amdgcn_mfma_f32_16x16x32_bf16(k1v, qf1, z, 0, 0, 0);
            s[c] = z;
        }

        // P = 2^(S*scale - 16); mask -> 0. No max tracking (scores bounded).
        const bool diag = (kt == qbase);
        #pragma unroll
        for (int c = 0; c < 4; ++c) {
            ushort4v pk;
            #pragma unroll
            for (int i = 0; i < 4; ++i) {
                float arg = s[c][i] * SCALE_LOG2 - FSHIFT;
                if (diag) {
                    int colg = kt + c * 16 + g4 + i;
                    if (colg > qrowA) arg = NEG_BIG;
                }
                float p = fast_exp2(arg);
                l_i += p;
                pk[i] = (unsigned short)f2bf(p);
            }
            *(ushort4v*)&Ps[wave][lr][c * 16 + g4] = pk;
        }

        // no barrier: Ps[wave] is wave-private, same-wave DS ops ordered
        #pragma unroll
        for (int kk = 0; kk < 2; ++kk) {
            short8 af = *(const short8*)&Ps[wave][lr][kk * 32 + lk];
            #pragma unroll
            for (int c = 0; c < 4; ++c) {
                short8 bf = *(const short8*)&Vt[c * 16 + lr][kk * 32 + lk];
                Oa[c] = __builtin_amdgcn_mfma_f32_16x16x32_bf16(af, bf, Oa[c], 0, 0, 0);
            }
        }
        __syncthreads();

        if (more) {
            *(short8*)&Ks[r0][c0] = ka;
            *(short8*)&Ks[r1][c1] = kb;
            *(short8*)&Vt[r0][c0] = va;
            *(short8*)&Vt[r1][c1] = vb;
            __syncthreads();
        }
    }

    // epilogue: finish row-sum (cross-quad), write partial O + l
    l_i += __shfl_xor(l_i, 16, 64);
    l_i += __shfl_xor(l_i, 32, 64);
    #pragma unroll
    for (int c = 0; c < 4; ++c) {
        #pragma unroll
        for (int i = 0; i < 4; ++i) {
            int rloc = wave * 16 + g4 + i;
            Ob[rloc * 64 + c * 16 + lr] = f2bf(Oa[c][i]);
        }
    }
    if (lane < 16) lrow[wave * 16 + lr] = l_i;
}

// ---------------------------------------------------------------------------
// Merge: O = (O0 + O1) / (l0 + l1)  (fixed shift -> directly summable).
// grid (32 bh, 32 qt), 256 threads.
// ---------------------------------------------------------------------------
__global__ __launch_bounds__(256) void attn_merge_kernel(
    const short* __restrict__ Opart, const float* __restrict__ lbuf,
    short* __restrict__ AO)
{
    const int bh = blockIdx.x, qt = blockIdx.y;
    const int b = bh >> 4, h = bh & 15;
    const int t = threadIdx.x;
    const int r = t >> 2, cb = (t & 3) * 16;

    const size_t s0 = (size_t)bh * 32 + qt;
    const size_t s1 = (size_t)(32 + bh) * 32 + qt;
    float inv = 1.0f / (lbuf[s0 * 64 + r] + lbuf[s1 * 64 + r]);

    const size_t o0 = s0 * 4096 + r * 64 + cb;
    const size_t o1 = s1 * 4096 + r * 64 + cb;
    short8 va0 = *(const short8*)&Opart[o0], vb0 = *(const short8*)&Opart[o0 + 8];
    short8 va1 = *(const short8*)&Opart[o1], vb1 = *(const short8*)&Opart[o1 + 8];
    short8 oa, ob;
    #pragma unroll
    for (int i = 0; i < 8; ++i) {
        oa[i] = f2bf((bf2f(va0[i]) + bf2f(va1[i])) * inv);
        ob[i] = f2bf((bf2f(vb0[i]) + bf2f(vb1[i])) * inv);
    }
    size_t ab = ((size_t)(b * TT + qt * 64 + r) << 10) + h * 64 + cb;
    *(short8*)&AO[ab] = oa;
    *(short8*)&AO[ab + 8] = ob;
}

// ---------------------------------------------------------------------------
// Fallback single-pass attention (fixed-shift) for small ws.
// grid (32 bh, 32 q_ord).
// ---------------------------------------------------------------------------
__global__ __launch_bounds__(256) void attn_kernel(
    const short* __restrict__ Q, const short* __restrict__ K,
    const short* __restrict__ V, short* __restrict__ AO)
{
    const int j = blockIdx.y, cdeal = j & 7, rdeal = j >> 3;
    const int qtile = (rdeal == 0) ? 31 - cdeal :
                      (rdeal == 1) ? 16 + cdeal :
                      (rdeal == 2) ? 15 - cdeal : cdeal;
    const int bh = blockIdx.x;
    const int qbase = qtile * 64;
    const short* Qp = Q + (size_t)bh * TT * 64;
    const short* Kp = K + (size_t)bh * TT * 64;
    const short* Vp = V + (size_t)bh * 64 * TT;

    __shared__ __align__(16) short Ks[64][72];
    __shared__ __align__(16) short Vt[64][72];
    __shared__ __align__(16) short Ps[4][16][72];

    const int tid = threadIdx.x;
    const int wave = tid >> 6, lane = tid & 63;
    const int lr = lane & 15;
    const int lk = (lane >> 4) * 8;
    const int g4 = (lane >> 4) * 4;
    const int b = bh >> 4, h = bh & 15;

    const int r0 = tid >> 3, c0 = (tid & 7) * 8;
    const int r1 = (tid + 256) >> 3, c1 = c0;

    const int qrowA = qbase + wave * 16 + lr;
    const short8 qf0 = *(const short8*)&Qp[(size_t)qrowA * 64 + lk];
    const short8 qf1 = *(const short8*)&Qp[(size_t)qrowA * 64 + 32 + lk];

    f32x4 Oa[4] = {{0,0,0,0},{0,0,0,0},{0,0,0,0},{0,0,0,0}};
    float l_i = 0.f;

    {
        short8 ka = *(const short8*)&Kp[(size_t)r0 * 64 + c0];
        short8 kb = *(const short8*)&Kp[(size_t)r1 * 64 + c1];
        short8 va = *(const short8*)&Vp[(size_t)r0 * TT + c0];
        short8 vb = *(const short8*)&Vp[(size_t)r1 * TT + c1];
        *(short8*)&Ks[r0][c0] = ka;
        *(short8*)&Ks[r1][c1] = kb;
        *(short8*)&Vt[r0][c0] = va;
        *(short8*)&Vt[r1][c1] = vb;
    }
    __syncthreads();

    const int kend = qbase + 64;
    for (int kt = 0; kt < kend; kt += 64) {
        const bool more = (kt + 64) < kend;
        short8 ka, kb, va, vb;
        if (more) {
            const int kn = kt + 64;
            ka = *(const short8*)&Kp[(size_t)(kn + r0) * 64 + c0];
            kb = *(const short8*)&Kp[(size_t)(kn + r1) * 64 + c1];
            va = *(const short8*)&Vp[(size_t)r0 * TT + kn + c0];
            vb = *(const short8*)&Vp[(size_t)r1 * TT + kn + c1];
        }

        f32x4 s[4];
        #pragma unroll
        for (int c = 0; c < 4; ++c) {
            f32x4 z = {0, 0, 0, 0};
            short8 k0v = *(const short8*)&Ks[c * 16 + lr][lk];
            short8 k1v = *(const short8*)&Ks[c * 16 + lr][32 + lk];
            z = __builtin_amdgcn_mfma_f32_16x16x32_bf16(k0v, qf0, z, 0, 0, 0);
            z = __builtin_amdgcn_mfma_f32_16x16x32_bf16(k1v, qf1, z, 0, 0, 0);
            s[c] = z;
        }

        const bool diag = (kt == qbase);
        #pragma unroll
        for (int c = 0; c < 4; ++c) {
            ushort4v pk;
            #pragma unroll
            for (int i = 0; i < 4; ++i) {
                float arg = s[c][i] * SCALE_LOG2 - FSHIFT;
                if (diag) {
                    int colg = kt + c * 16 + g4 + i;
                    if (colg > qrowA) arg = NEG_BIG;
                }
                float p = fast_exp2(arg);
                l_i += p;
                pk[i] = (unsigned short)f2bf(p);
            }
            *(ushort4v*)&Ps[wave][lr][c * 16 + g4] = pk;
        }

        #pragma unroll
        for (int kk = 0; kk < 2; ++kk) {
            short8 af = *(const short8*)&Ps[wave][lr][kk * 32 + lk];
            #pragma unroll
            for (int c = 0; c < 4; ++c) {
                short8 bf = *(const short8*)&Vt[c * 16 + lr][kk * 32 + lk];
                Oa[c] = __builtin_amdgcn_mfma_f32_16x16x32_bf16(af, bf, Oa[c], 0, 0, 0);
            }
        }
        __syncthreads();

        if (more) {
            *(short8*)&Ks[r0][c0] = ka;
            *(short8*)&Ks[r1][c1] = kb;
            *(short8*)&Vt[r0][c0] = va;
            *(short8*)&Vt[r1][c1] = vb;
            __syncthreads();
        }
    }

    l_i += __shfl_xor(l_i, 16, 64);
    l_i += __shfl_xor(l_i, 32, 64);
    float lb[4];
    #pragma unroll
    for (int i = 0; i < 4; ++i) lb[i] = 1.0f / __shfl(l_i, g4 + i, 64);
    #pragma unroll
    for (int c = 0; c < 4; ++c) {
        #pragma unroll
        for (int i = 0; i < 4; ++i) {
            int qr = qbase + wave * 16 + g4 + i;
            float v = Oa[c][i] * lb[i];
            AO[((size_t)(b * TT + qr) << 10) + h * 64 + c * 16 + lr] = f2bf(v);
        }
    }
}

// ---------------------------------------------------------------------------
extern "C" void kernel_launch(void* const* d_in, const int* in_sizes, int n_in,
                              void* d_out, int out_size, void* d_ws, size_t ws_size,
                              hipStream_t stream)
{
    char* ws = (char*)d_ws;
    const size_t XB  = (size_t)TM * TD * 2;   // 8 MiB bf16 x
    const size_t WB  = (size_t)TD * TD * 2;   // 2 MiB bf16 weight
    const size_t BUF = (size_t)TM * TD * 2;   // 8 MiB activation

    short* xb  = (short*)(ws + 256);
    short* Wqb = (short*)(ws + 256 + XB);
    short* Wkb = (short*)(ws + 256 + XB + WB);
    short* Wvb = (short*)(ws + 256 + XB + 2 * WB);
    short* Wob = (short*)(ws + 256 + XB + 3 * WB);
    char*  act = ws + 256 + XB + 4 * WB;
    short* Qb = (short*)(act);
    short* Kb = (short*)(act + BUF);
    short* Vb = (short*)(act + 2 * BUF);   // V^T [B,H,64,T]
    short* Ab = (short*)(act + 3 * BUF);
    char*  part = act + 4 * BUF;
    short* Opart = (short*)part;                               // 16 MiB
    float* lbuf  = (float*)(part + (size_t)16 * 1024 * 1024);  // 512 KiB

    const size_t need = 256 + XB + 4 * WB + 4 * BUF +
                        (size_t)16 * 1024 * 1024 + 524288;
    const bool splitS = (ws_size >= need);   // constant across calls: graph-safe

    dim3 blk(256);
    convert_all_kernel<<<dim3(512 + 4 * 128), blk, 0, stream>>>(
        d_in[0], d_in[1], d_in[2], d_in[3], d_in[4], xb, Wqb, Wkb, Wvb, Wob);
    qkv_gemm_kernel<<<dim3(TM / 128, TD / 128, 3), blk, 0, stream>>>(xb, Wqb, Wkb, Wvb, Qb, Kb, Vb);
    if (splitS) {
        attn_split_kernel<<<dim3(32, 64), blk, 0, stream>>>(Qb, Kb, Vb, Opart, lbuf);
        attn_merge_kernel<<<dim3(32, 32), blk, 0, stream>>>(Opart, lbuf, Ab);
    } else {
        attn_kernel<<<dim3(32, 32), blk, 0, stream>>>(Qb, Kb, Vb, Ab);
    }
    out_gemm_kernel<<<dim3(TM / 64, TD / 128), blk, 0, stream>>>(
        Ab, Wob, d_out, (const unsigned short*)d_in[0]);
}

// Round 12
// 183.804 us; speedup vs baseline: 1.7136x; 1.0225x over previous
//
#include <hip/hip_runtime.h>
#include <hip/hip_bf16.h>

// Problem: B=2, T=2048, D=1024, H=16, HD=64.
// Runtime-detect fp32 vs bf16 inputs (inline, per-wave); canonicalize to bf16.
// convert_all -> qkv gemm (128x128 reg-prefetch; Q,K:[B,H,T,64] via LDS-
// transpose epilogue; V:[B,H,64,T]) -> split-S flash attention (fixed-shift
// softmax, K/V LDS double-buffer w/ 1 barrier/tile, MFMA ones-row l) ->
// merge -> out gemm (64x128).

#define TB 2
#define TT 2048
#define TD 1024
#define TH 16
#define TM (TB * TT) // 4096

#define NEG_BIG (-1e30f)
#define SCALE_LOG2 0.18033688f  // (1/sqrt(64)) * log2(e)
#define FSHIFT 16.0f            // fixed softmax shift (exact; cancels in O/l)
#define BF16_ONE ((short)0x3F80)

typedef __attribute__((ext_vector_type(8))) short short8;
typedef __attribute__((ext_vector_type(4))) float f32x4;
typedef __attribute__((ext_vector_type(4))) unsigned short ushort4v;

__device__ __forceinline__ short f2bf(float f) {
    __hip_bfloat16 h = __float2bfloat16(f);
    return __builtin_bit_cast(short, h);
}

__device__ __forceinline__ float bf2f(short u) {
    unsigned int x = ((unsigned int)(unsigned short)u) << 16;
    return __builtin_bit_cast(float, x);
}

__device__ __forceinline__ float fast_exp2(float x) {
#if __has_builtin(__builtin_amdgcn_exp2f)
    return __builtin_amdgcn_exp2f(x);
#else
    return exp2f(x);
#endif
}

// Inline dtype detect: sample even u16s of x; uniform per wave.
__device__ __forceinline__ int detect_bf16(const unsigned short* xq) {
    int lane = threadIdx.x & 63;
    unsigned short u = xq[lane * 2];
    int e = (u >> 7) & 0xFF;
    int sane = ((e >= 100 && e <= 145) || u == 0) ? 1 : 0;
    unsigned long long b = __ballot(sane);
    return (__popcll(b) >= 48) ? 1 : 0; // 1 = bf16, 0 = fp32
}

// ---------------------------------------------------------------------------
// One dispatch converts x + 4 weights; 8192 elems/block.
// ---------------------------------------------------------------------------
__global__ __launch_bounds__(256) void convert_all_kernel(
    const void* __restrict__ x,  const void* __restrict__ wq,
    const void* __restrict__ wk, const void* __restrict__ wv,
    const void* __restrict__ wo,
    short* __restrict__ xb, short* __restrict__ wqb, short* __restrict__ wkb,
    short* __restrict__ wvb, short* __restrict__ wob)
{
    const int f = detect_bf16((const unsigned short*)x);
    int bid = blockIdx.x;
    const void* src; short* dst; int base;
    if (bid < 512) { src = x; dst = xb; base = bid; }
    else {
        int w = (bid - 512) >> 7, lb = (bid - 512) & 127;
        src = (w == 0) ? wq : (w == 1) ? wk : (w == 2) ? wv : wo;
        dst = (w == 0) ? wqb : (w == 1) ? wkb : (w == 2) ? wvb : wob;
        base = lb;
    }
    int i0 = base * 8192 + (int)threadIdx.x * 8;
    #pragma unroll
    for (int r = 0; r < 4; ++r) {
        int i = i0 + r * 2048;
        if (f) {
            *(short8*)(dst + i) = *(const short8*)((const short*)src + i);
        } else {
            const float* s = (const float*)src + i;
            short8 o;
            #pragma unroll
            for (int j = 0; j < 8; ++j) o[j] = f2bf(s[j]);
            *(short8*)(dst + i) = o;
        }
    }
}

// ---------------------------------------------------------------------------
// GEMM core, register-prefetch pipeline. C[m,n] = sum_k A[m,k]*B[n,k].
// Tile: MROWS x 128, BK=64, K=1024. 4 waves (2x2). XOR chunk swizzle.
// ---------------------------------------------------------------------------
template<int MROWS>
__device__ __forceinline__ void gemm_core_regpf(
    const short* __restrict__ A, const short* __restrict__ B,
    short* SM, int mbase, int nbase, f32x4 (*acc)[4])
{
    constexpr int TA = MROWS / 32;
    short* As = SM;
    short* Bs = SM + MROWS * 64;

    const int tid = threadIdx.x;
    const int wave = tid >> 6, lane = tid & 63;
    const int wm = wave >> 1, wn = wave & 1;
    const int lr = lane & 15;
    const int srow = lane >> 3, jcl = lane & 7;

    #pragma unroll
    for (int a = 0; a < TA; ++a)
        #pragma unroll
        for (int b = 0; b < 4; ++b) acc[a][b] = (f32x4){0, 0, 0, 0};

    short8 an[TA], bn[4];
    #pragma unroll
    for (int t = 0; t < TA; ++t) {
        int w = wave * TA + t, r = w * 8 + srow, jc = jcl ^ (r & 7);
        an[t] = *(const short8*)&A[(size_t)(mbase + r) * TD + jc * 8];
    }
    #pragma unroll
    for (int t = 0; t < 4; ++t) {
        int w = wave * 4 + t, r = w * 8 + srow, jc = jcl ^ (r & 7);
        bn[t] = *(const short8*)&B[(size_t)(nbase + r) * TD + jc * 8];
    }
    #pragma unroll
    for (int t = 0; t < TA; ++t) *(short8*)&As[(wave * TA + t) * 512 + lane * 8] = an[t];
    #pragma unroll
    for (int t = 0; t < 4; ++t)  *(short8*)&Bs[(wave * 4 + t) * 512 + lane * 8] = bn[t];
    __syncthreads();

    for (int k0 = 0; k0 < TD; k0 += 64) {
        const bool more = (k0 + 64) < TD;
        if (more) {
            #pragma unroll
            for (int t = 0; t < TA; ++t) {
                int w = wave * TA + t, r = w * 8 + srow, jc = jcl ^ (r & 7);
                an[t] = *(const short8*)&A[(size_t)(mbase + r) * TD + k0 + 64 + jc * 8];
            }
            #pragma unroll
            for (int t = 0; t < 4; ++t) {
                int w = wave * 4 + t, r = w * 8 + srow, jc = jcl ^ (r & 7);
                bn[t] = *(const short8*)&B[(size_t)(nbase + r) * TD + k0 + 64 + jc * 8];
            }
        }
        #pragma unroll
        for (int kk = 0; kk < 64; kk += 32) {
            const int cc = (kk >> 3) + (lane >> 4);
            const int csw = (cc ^ (lr & 7)) << 3;
            short8 af[TA], bf[4];
            #pragma unroll
            for (int a = 0; a < TA; ++a)
                af[a] = *(const short8*)&As[(wm * (MROWS / 2) + a * 16 + lr) * 64 + csw];
            #pragma unroll
            for (int b = 0; b < 4; ++b)
                bf[b] = *(const short8*)&Bs[(wn * 64 + b * 16 + lr) * 64 + csw];
            #pragma unroll
            for (int a = 0; a < TA; ++a)
                #pragma unroll
                for (int b = 0; b < 4; ++b)
                    acc[a][b] = __builtin_amdgcn_mfma_f32_16x16x32_bf16(af[a], bf[b], acc[a][b], 0, 0, 0);
        }
        __syncthreads();
        if (more) {
            #pragma unroll
            for (int t = 0; t < TA; ++t) *(short8*)&As[(wave * TA + t) * 512 + lane * 8] = an[t];
            #pragma unroll
            for (int t = 0; t < 4; ++t)  *(short8*)&Bs[(wave * 4 + t) * 512 + lane * 8] = bn[t];
            __syncthreads();
        }
    }
}

// ---------------------------------------------------------------------------
// QKV projection; 128x128 tiles, grid (32, 8, 3).  [R10 version]
// Q,K out [B,H,T,64] via LDS-transposed coalesced epilogue; V out [B,H,64,T].
// ---------------------------------------------------------------------------
__global__ __launch_bounds__(256, 3) void qkv_gemm_kernel(
    const short* __restrict__ x,
    const short* __restrict__ Wq, const short* __restrict__ Wk,
    const short* __restrict__ Wv,
    short* __restrict__ Qo, short* __restrict__ Ko, short* __restrict__ Vo)
{
    const short* W = (blockIdx.z == 0) ? Wq : (blockIdx.z == 1) ? Wk : Wv;
    short* Out = (blockIdx.z == 0) ? Qo : (blockIdx.z == 1) ? Ko : Vo;
    const bool transposeV = (blockIdx.z == 2);

    __shared__ __align__(16) short SM[128 * 64 * 2];

    const int mbase = blockIdx.x * 128, nbase = blockIdx.y * 128;
    f32x4 acc[4][4];
    gemm_core_regpf<128>(x, W, SM, mbase, nbase, acc);

    const int tid = threadIdx.x;
    const int wave = tid >> 6, lane = tid & 63;
    const int wm = wave >> 1, wn = wave & 1;
    const int lr = lane & 15;
    const int g4 = (lane >> 4) * 4;

    if (transposeV) {
        #pragma unroll
        for (int a = 0; a < 4; ++a) {
            #pragma unroll
            for (int b = 0; b < 4; ++b) {
                int m0 = mbase + wm * 64 + a * 16 + g4;
                int n = nbase + wn * 64 + b * 16 + lr;
                int bb = m0 >> 11, t0 = m0 & (TT - 1);
                int h = n >> 6, hd = n & 63;
                ushort4v pk;
                #pragma unroll
                for (int i = 0; i < 4; ++i) pk[i] = (unsigned short)f2bf(acc[a][b][i]);
                *(ushort4v*)&Out[((size_t)(bb * TH + h) * 64 + hd) * TT + t0] = pk;
            }
        }
    } else {
        short* Cs = SM;
        #pragma unroll
        for (int p = 0; p < 2; ++p) {
            __syncthreads();
            if (wn == p) {
                #pragma unroll
                for (int a = 0; a < 4; ++a)
                    #pragma unroll
                    for (int b = 0; b < 4; ++b)
                        #pragma unroll
                        for (int i = 0; i < 4; ++i) {
                            int ml = wm * 64 + a * 16 + g4 + i;
                            int nl = b * 16 + lr;
                            Cs[ml * 72 + nl] = f2bf(acc[a][b][i]);
                        }
            }
            __syncthreads();
            int tl = tid >> 1, hc = (tid & 1) * 32;
            int h = (nbase >> 6) + p;
            int m = mbase + tl;
            int bb = m >> 11, t = m & (TT - 1);
            size_t base = (((size_t)(bb * TH + h) * TT + t) << 6) + hc;
            #pragma unroll
            for (int q = 0; q < 4; ++q)
                *(short8*)&Out[base + q * 8] = *(short8*)&Cs[tl * 72 + hc + q * 8];
        }
    }
}

// ---------------------------------------------------------------------------
// Output projection; 64x128 tiles, grid (64, 8).
// ---------------------------------------------------------------------------
__global__ __launch_bounds__(256, 2) void out_gemm_kernel(
    const short* __restrict__ A, const short* __restrict__ W,
    void* __restrict__ C, const unsigned short* __restrict__ xq)
{
    const int f = detect_bf16(xq);

    __shared__ __align__(16) short SM[64 * 64 + 128 * 64];

    const int mbase = blockIdx.x * 64, nbase = blockIdx.y * 128;
    f32x4 acc[2][4];
    gemm_core_regpf<64>(A, W, SM, mbase, nbase, acc);

    const int tid = threadIdx.x;
    const int wave = tid >> 6, lane = tid & 63;
    const int wm = wave >> 1, wn = wave & 1;
    const int lr = lane & 15;
    const int g4 = (lane >> 4) * 4;

    #pragma unroll
    for (int a = 0; a < 2; ++a) {
        #pragma unroll
        for (int b = 0; b < 4; ++b) {
            #pragma unroll
            for (int i = 0; i < 4; ++i) {
                int m = mbase + wm * 32 + a * 16 + g4 + i;
                int n = nbase + wn * 64 + b * 16 + lr;
                if (f) ((short*)C)[(size_t)m * TD + n] = f2bf(acc[a][b][i]);
                else   ((float*)C)[(size_t)m * TD + n] = acc[a][b][i];
            }
        }
    }
}

// ---------------------------------------------------------------------------
// Split-S flash attention, fixed-shift softmax, K/V LDS DOUBLE-BUFFER with
// ONE barrier per k-tile, l computed on the MFMA pipe via ones-row B-frag.
// grid (32 bh, 64 work), block 256, 64 q-rows. Snake-dealt (qtile, half).
// ---------------------------------------------------------------------------
__global__ __launch_bounds__(256) void attn_split_kernel(
    const short* __restrict__ Q, const short* __restrict__ K,
    const short* __restrict__ V, short* __restrict__ Opart,
    float* __restrict__ lbuf)
{
    const int j = blockIdx.y;
    const int rd = j >> 3, cd = j & 7;
    const int idx = rd * 8 + ((rd & 1) ? (7 - cd) : cd);
    const int qt = 31 - (idx >> 1);
    const int half = idx & 1;
    const int bh = blockIdx.x;

    const int nt = qt + 1, nt0 = (qt + 2) >> 1;
    const int tb = half ? nt0 : 0;
    const int te = half ? nt : nt0;

    const int tid = threadIdx.x;
    const size_t pslot = (size_t)(half * 32 + bh) * 32 + qt;
    float* lrow = lbuf + pslot * 64;
    short* Ob = Opart + pslot * 4096;

    if (tb >= te) { // empty half: zero contribution
        short8 z8 = {0, 0, 0, 0, 0, 0, 0, 0};
        *(short8*)&Ob[tid * 16] = z8;
        *(short8*)&Ob[tid * 16 + 8] = z8;
        if (tid < 64) lrow[tid] = 0.f;
        return;
    }

    const int qbase = qt * 64;
    const short* Qp = Q + (size_t)bh * TT * 64;
    const short* Kp = K + (size_t)bh * TT * 64;
    const short* Vp = V + (size_t)bh * 64 * TT;   // V^T: [64][TT]

    __shared__ __align__(16) short Ks[2][64][72];
    __shared__ __align__(16) short Vt[2][64][72];
    __shared__ __align__(16) short Ps[4][16][72];

    const int wave = tid >> 6, lane = tid & 63;
    const int lr = lane & 15;
    const int lk = (lane >> 4) * 8;
    const int g4 = (lane >> 4) * 4;

    const int r0 = tid >> 3, c0 = (tid & 7) * 8;
    const int r1 = (tid + 256) >> 3, c1 = c0;

    const int qrowA = qbase + wave * 16 + lr;
    const short8 qf0 = *(const short8*)&Qp[(size_t)qrowA * 64 + lk];
    const short8 qf1 = *(const short8*)&Qp[(size_t)qrowA * 64 + 32 + lk];

    short8 ones8;
    #pragma unroll
    for (int i = 0; i < 8; ++i) ones8[i] = BF16_ONE;

    f32x4 Oa[4] = {{0,0,0,0},{0,0,0,0},{0,0,0,0},{0,0,0,0}};
    f32x4 La = {0, 0, 0, 0};   // row-sums of P via MFMA ones-column

    const int kb64 = tb * 64, ke64 = te * 64;
    // prologue: stage first tile into buf 0
    {
        *(short8*)&Ks[0][r0][c0] = *(const short8*)&Kp[(size_t)(kb64 + r0) * 64 + c0];
        *(short8*)&Ks[0][r1][c1] = *(const short8*)&Kp[(size_t)(kb64 + r1) * 64 + c1];
        *(short8*)&Vt[0][r0][c0] = *(const short8*)&Vp[(size_t)r0 * TT + kb64 + c0];
        *(short8*)&Vt[0][r1][c1] = *(const short8*)&Vp[(size_t)r1 * TT + kb64 + c1];
    }
    __syncthreads();

    int buf = 0;
    for (int kt = kb64; kt < ke64; kt += 64) {
        const bool more = (kt + 64) < ke64;
        short8 ka, kb, va, vb;
        if (more) {
            const int kn = kt + 64;
            ka = *(const short8*)&Kp[(size_t)(kn + r0) * 64 + c0];
            kb = *(const short8*)&Kp[(size_t)(kn + r1) * 64 + c1];
            va = *(const short8*)&Vp[(size_t)r0 * TT + kn + c0];
            vb = *(const short8*)&Vp[(size_t)r1 * TT + kn + c1];
        }

        // S^T = K Q^T
        f32x4 s[4];
        #pragma unroll
        for (int c = 0; c < 4; ++c) {
            f32x4 z = {0, 0, 0, 0};
            short8 k0v = *(const short8*)&Ks[buf][c * 16 + lr][lk];
            short8 k1v = *(const short8*)&Ks[buf][c * 16 + lr][32 + lk];
            z = __builtin_amdgcn_mfma_f32_16x16x32_bf16(k0v, qf0, z, 0, 0, 0);
            z = __builtin_amdgcn_mfma_f32_16x16x32_bf16(k1v, qf1, z, 0, 0, 0);
            s[c] = z;
        }

        // P = 2^(S*scale - 16); mask -> 0 (exact fixed-shift softmax)
        const bool diag = (kt == qbase);
        #pragma unroll
        for (int c = 0; c < 4; ++c) {
            ushort4v pk;
            #pragma unroll
            for (int i = 0; i < 4; ++i) {
                float arg = s[c][i] * SCALE_LOG2 - FSHIFT;
                if (diag) {
                    int colg = kt + c * 16 + g4 + i;
                    if (colg > qrowA) arg = NEG_BIG;
                }
                pk[i] = (unsigned short)f2bf(fast_exp2(arg));
            }
            *(ushort4v*)&Ps[wave][lr][c * 16 + g4] = pk;
        }

        // O += P V ; La += P * ones (row-sums on the matrix pipe)
        #pragma unroll
        for (int kk = 0; kk < 2; ++kk) {
            short8 af = *(const short8*)&Ps[wave][lr][kk * 32 + lk];
            #pragma unroll
            for (int c = 0; c < 4; ++c) {
                short8 bf = *(const short8*)&Vt[buf][c * 16 + lr][kk * 32 + lk];
                Oa[c] = __builtin_amdgcn_mfma_f32_16x16x32_bf16(af, bf, Oa[c], 0, 0, 0);
            }
            La = __builtin_amdgcn_mfma_f32_16x16x32_bf16(af, ones8, La, 0, 0, 0);
        }

        // stage next tile into the alternate buffer, then ONE barrier
        if (more) {
            *(short8*)&Ks[buf ^ 1][r0][c0] = ka;
            *(short8*)&Ks[buf ^ 1][r1][c1] = kb;
            *(short8*)&Vt[buf ^ 1][r0][c0] = va;
            *(short8*)&Vt[buf ^ 1][r1][c1] = vb;
        }
        __syncthreads();
        buf ^= 1;
    }

    // epilogue: write unnormalized partial O + l (La rows == Oa rows)
    #pragma unroll
    for (int c = 0; c < 4; ++c) {
        #pragma unroll
        for (int i = 0; i < 4; ++i) {
            int rloc = wave * 16 + g4 + i;
            Ob[rloc * 64 + c * 16 + lr] = f2bf(Oa[c][i]);
        }
    }
    if (lr == 0) {
        #pragma unroll
        for (int i = 0; i < 4; ++i) lrow[wave * 16 + g4 + i] = La[i];
    }
}

// ---------------------------------------------------------------------------
// Merge: O = (O0 + O1) / (l0 + l1). grid (32 bh, 32 qt), 256 threads.
// ---------------------------------------------------------------------------
__global__ __launch_bounds__(256) void attn_merge_kernel(
    const short* __restrict__ Opart, const float* __restrict__ lbuf,
    short* __restrict__ AO)
{
    const int bh = blockIdx.x, qt = blockIdx.y;
    const int b = bh >> 4, h = bh & 15;
    const int t = threadIdx.x;
    const int r = t >> 2, cb = (t & 3) * 16;

    const size_t s0 = (size_t)bh * 32 + qt;
    const size_t s1 = (size_t)(32 + bh) * 32 + qt;
    float inv = 1.0f / (lbuf[s0 * 64 + r] + lbuf[s1 * 64 + r]);

    const size_t o0 = s0 * 4096 + r * 64 + cb;
    const size_t o1 = s1 * 4096 + r * 64 + cb;
    short8 va0 = *(const short8*)&Opart[o0], vb0 = *(const short8*)&Opart[o0 + 8];
    short8 va1 = *(const short8*)&Opart[o1], vb1 = *(const short8*)&Opart[o1 + 8];
    short8 oa, ob;
    #pragma unroll
    for (int i = 0; i < 8; ++i) {
        oa[i] = f2bf((bf2f(va0[i]) + bf2f(va1[i])) * inv);
        ob[i] = f2bf((bf2f(vb0[i]) + bf2f(vb1[i])) * inv);
    }
    size_t ab = ((size_t)(b * TT + qt * 64 + r) << 10) + h * 64 + cb;
    *(short8*)&AO[ab] = oa;
    *(short8*)&AO[ab + 8] = ob;
}

// ---------------------------------------------------------------------------
// Fallback single-pass attention (fixed-shift + ones-row l) for small ws.
// ---------------------------------------------------------------------------
__global__ __launch_bounds__(256) void attn_kernel(
    const short* __restrict__ Q, const short* __restrict__ K,
    const short* __restrict__ V, short* __restrict__ AO)
{
    const int j = blockIdx.y, cdeal = j & 7, rdeal = j >> 3;
    const int qtile = (rdeal == 0) ? 31 - cdeal :
                      (rdeal == 1) ? 16 + cdeal :
                      (rdeal == 2) ? 15 - cdeal : cdeal;
    const int bh = blockIdx.x;
    const int qbase = qtile * 64;
    const short* Qp = Q + (size_t)bh * TT * 64;
    const short* Kp = K + (size_t)bh * TT * 64;
    const short* Vp = V + (size_t)bh * 64 * TT;

    __shared__ __align__(16) short Ks[64][72];
    __shared__ __align__(16) short Vt[64][72];
    __shared__ __align__(16) short Ps[4][16][72];

    const int tid = threadIdx.x;
    const int wave = tid >> 6, lane = tid & 63;
    const int lr = lane & 15;
    const int lk = (lane >> 4) * 8;
    const int g4 = (lane >> 4) * 4;
    const int b = bh >> 4, h = bh & 15;

    const int r0 = tid >> 3, c0 = (tid & 7) * 8;
    const int r1 = (tid + 256) >> 3, c1 = c0;

    const int qrowA = qbase + wave * 16 + lr;
    const short8 qf0 = *(const short8*)&Qp[(size_t)qrowA * 64 + lk];
    const short8 qf1 = *(const short8*)&Qp[(size_t)qrowA * 64 + 32 + lk];

    short8 ones8;
    #pragma unroll
    for (int i = 0; i < 8; ++i) ones8[i] = BF16_ONE;

    f32x4 Oa[4] = {{0,0,0,0},{0,0,0,0},{0,0,0,0},{0,0,0,0}};
    f32x4 La = {0, 0, 0, 0};

    {
        *(short8*)&Ks[r0][c0] = *(const short8*)&Kp[(size_t)r0 * 64 + c0];
        *(short8*)&Ks[r1][c1] = *(const short8*)&Kp[(size_t)r1 * 64 + c1];
        *(short8*)&Vt[r0][c0] = *(const short8*)&Vp[(size_t)r0 * TT + c0];
        *(short8*)&Vt[r1][c1] = *(const short8*)&Vp[(size_t)r1 * TT + c1];
    }
    __syncthreads();

    const int kend = qbase + 64;
    for (int kt = 0; kt < kend; kt += 64) {
        const bool more = (kt + 64) < kend;
        short8 ka, kb, va, vb;
        if (more) {
            const int kn = kt + 64;
            ka = *(const short8*)&Kp[(size_t)(kn + r0) * 64 + c0];
            kb = *(const short8*)&Kp[(size_t)(kn + r1) * 64 + c1];
            va = *(const short8*)&Vp[(size_t)r0 * TT + kn + c0];
            vb = *(const short8*)&Vp[(size_t)r1 * TT + kn + c1];
        }

        f32x4 s[4];
        #pragma unroll
        for (int c = 0; c < 4; ++c) {
            f32x4 z = {0, 0, 0, 0};
            short8 k0v = *(const short8*)&Ks[c * 16 + lr][lk];
            short8 k1v = *(const short8*)&Ks[c * 16 + lr][32 + lk];
            z = __builtin_amdgcn_mfma_f32_16x16x32_bf16(k0v, qf0, z, 0, 0, 0);
            z = __builtin_amdgcn_mfma_f32_16x16x32_bf16(k1v, qf1, z, 0, 0, 0);
            s[c] = z;
        }

        const bool diag = (kt == qbase);
        #pragma unroll
        for (int c = 0; c < 4; ++c) {
            ushort4v pk;
            #pragma unroll
            for (int i = 0; i < 4; ++i) {
                float arg = s[c][i] * SCALE_LOG2 - FSHIFT;
                if (diag) {
                    int colg = kt + c * 16 + g4 + i;
                    if (colg > qrowA) arg = NEG_BIG;
                }
                pk[i] = (unsigned short)f2bf(fast_exp2(arg));
            }
            *(ushort4v*)&Ps[wave][lr][c * 16 + g4] = pk;
        }

        #pragma unroll
        for (int kk = 0; kk < 2; ++kk) {
            short8 af = *(const short8*)&Ps[wave][lr][kk * 32 + lk];
            #pragma unroll
            for (int c = 0; c < 4; ++c) {
                short8 bf = *(const short8*)&Vt[c * 16 + lr][kk * 32 + lk];
                Oa[c] = __builtin_amdgcn_mfma_f32_16x16x32_bf16(af, bf, Oa[c], 0, 0, 0);
            }
            La = __builtin_amdgcn_mfma_f32_16x16x32_bf16(af, ones8, La, 0, 0, 0);
        }
        __syncthreads();

        if (more) {
            *(short8*)&Ks[r0][c0] = ka;
            *(short8*)&Ks[r1][c1] = kb;
            *(short8*)&Vt[r0][c0] = va;
            *(short8*)&Vt[r1][c1] = vb;
            __syncthreads();
        }
    }

    #pragma unroll
    for (int c = 0; c < 4; ++c) {
        #pragma unroll
        for (int i = 0; i < 4; ++i) {
            int qr = qbase + wave * 16 + g4 + i;
            float v = Oa[c][i] / La[i];
            AO[((size_t)(b * TT + qr) << 10) + h * 64 + c * 16 + lr] = f2bf(v);
        }
    }
}

// ---------------------------------------------------------------------------
extern "C" void kernel_launch(void* const* d_in, const int* in_sizes, int n_in,
                              void* d_out, int out_size, void* d_ws, size_t ws_size,
                              hipStream_t stream)
{
    char* ws = (char*)d_ws;
    const size_t XB  = (size_t)TM * TD * 2;   // 8 MiB bf16 x
    const size_t WB  = (size_t)TD * TD * 2;   // 2 MiB bf16 weight
    const size_t BUF = (size_t)TM * TD * 2;   // 8 MiB activation

    short* xb  = (short*)(ws + 256);
    short* Wqb = (short*)(ws + 256 + XB);
    short* Wkb = (short*)(ws + 256 + XB + WB);
    short* Wvb = (short*)(ws + 256 + XB + 2 * WB);
    short* Wob = (short*)(ws + 256 + XB + 3 * WB);
    char*  act = ws + 256 + XB + 4 * WB;
    short* Qb = (short*)(act);
    short* Kb = (short*)(act + BUF);
    short* Vb = (short*)(act + 2 * BUF);   // V^T [B,H,64,T]
    short* Ab = (short*)(act + 3 * BUF);
    char*  part = act + 4 * BUF;
    short* Opart = (short*)part;                               // 16 MiB
    float* lbuf  = (float*)(part + (size_t)16 * 1024 * 1024);  // 512 KiB

    const size_t need = 256 + XB + 4 * WB + 4 * BUF +
                        (size_t)16 * 1024 * 1024 + 524288;
    const bool splitS = (ws_size >= need);   // constant across calls: graph-safe

    dim3 blk(256);
    convert_all_kernel<<<dim3(512 + 4 * 128), blk, 0, stream>>>(
        d_in[0], d_in[1], d_in[2], d_in[3], d_in[4], xb, Wqb, Wkb, Wvb, Wob);
    qkv_gemm_kernel<<<dim3(TM / 128, TD / 128, 3), blk, 0, stream>>>(xb, Wqb, Wkb, Wvb, Qb, Kb, Vb);
    if (splitS) {
        attn_split_kernel<<<dim3(32, 64), blk, 0, stream>>>(Qb, Kb, Vb, Opart, lbuf);
        attn_merge_kernel<<<dim3(32, 32), blk, 0, stream>>>(Opart, lbuf, Ab);
    } else {
        attn_kernel<<<dim3(32, 32), blk, 0, stream>>>(Qb, Kb, Vb, Ab);
    }
    out_gemm_kernel<<<dim3(TM / 64, TD / 128), blk, 0, stream>>>(
        Ab, Wob, d_out, (const unsigned short*)d_in[0]);
}